// Round 6
// baseline (10488.290 us; speedup 1.0000x reference)
//
#include <hip/hip_runtime.h>

typedef unsigned short u16;
typedef unsigned int   u32;

#define NN 2048

__device__ __forceinline__ float b2f(u16 u){ union { u32 i; float f; } x; x.i = ((u32)u)<<16; return x.f; }
// dtype-adaptive load: bf==1 -> bf16 storage, bf==0 -> fp32 storage
__device__ __forceinline__ float ldf(const void* p, size_t i, int bf){
  return bf ? b2f(((const u16*)p)[i]) : ((const float*)p)[i];
}

// ---------------- diagnostic sentinel (f32 out) ------------------------------
__global__ __launch_bounds__(256) void sentinel_kernel(float* __restrict__ out, float val){
  int g = blockIdx.x*256 + threadIdx.x;
  if (g < NN*64) out[g] = val;
}

// ---------------- dtype probe: fp32 A_pos words are exactly 0 / 0x3F800000 --
__global__ __launch_bounds__(256) void probe_kernel(const u32* __restrict__ ap, int* __restrict__ flag){
  __shared__ int sb[256];
  int bad = 0;
  for (int i = threadIdx.x; i < 65536; i += 256){
    u32 w = ap[i];
    if (w != 0u && w != 0x3F800000u) bad++;
  }
  sb[threadIdx.x] = bad;
  __syncthreads();
  if (threadIdx.x == 0){
    int t = 0;
    for (int k = 0; k < 256; ++k) t += sb[k];
    *flag = (t > 0) ? 1 : 0;
  }
}

// ---------------- x -> f32 ---------------------------------------------------
__global__ __launch_bounds__(256) void convx_kernel(const void* __restrict__ x, float* __restrict__ xf,
                                                    const int* __restrict__ flag){
  int bf = *flag;
  size_t i = (size_t)blockIdx.x*256 + threadIdx.x;   // 2048*512
  xf[i] = ldf(x, i, bf);
}

// ---------------- binarize adjacencies to dense f32 -------------------------
__global__ __launch_bounds__(256) void binz_kernel(const void* __restrict__ An, const void* __restrict__ Ap,
                                                   float* __restrict__ lastB, float* __restrict__ uniB,
                                                   float* __restrict__ Apb, const int* __restrict__ flag){
  int bf = *flag;
  size_t e = (size_t)blockIdx.x*256 + threadIdx.x;   // 2048*2048
  float a = (ldf(An, e, bf) > 0.f) ? 1.f : 0.f;
  lastB[e] = a;
  uniB[e]  = a;
  Apb[e]   = (ldf(Ap, e, bf) > 0.f) ? 1.f : 0.f;
}

// ---------------- literal expansion: new = (last @ Apb) > 0 ; union = max ---
__global__ __launch_bounds__(256) void expandf_kernel(const float* __restrict__ last, const float* __restrict__ Apb,
                                                      float* __restrict__ nw, float* __restrict__ uni){
  int g = blockIdx.x*256 + threadIdx.x;   // 4M outputs
  int j = g & 2047;
  int i = g >> 11;
  const float* a = last + (size_t)i*NN;
  float acc = 0.f;
#pragma unroll 4
  for (int k = 0; k < NN; ++k) acc = fmaf(a[k], Apb[(size_t)k*NN + j], acc);
  float nv = (acc > 0.f) ? 1.f : 0.f;
  nw[g]  = nv;
  uni[g] = fmaxf(uni[g], nv);
}

// ---------------- deg -> dinv (ROW sums of dense union, per listing) --------
__global__ __launch_bounds__(256) void degk_kernel(const float* __restrict__ uni, float* __restrict__ dinv){
  __shared__ float sd[256];
  int i = blockIdx.x;
  float s = 0.f;
  for (int k = threadIdx.x; k < NN; k += 256) s += uni[(size_t)i*NN + k];
  sd[threadIdx.x] = s;
  __syncthreads();
  for (int d = 128; d > 0; d >>= 1){
    if (threadIdx.x < d) sd[threadIdx.x] += sd[threadIdx.x + d];
    __syncthreads();
  }
  if (threadIdx.x == 0) dinv[i] = 1.0f / sqrtf(sd[0] + 1.0f);
}

// --------------- dumb f32 GEMM: C[i][n] = sum_k A[i][k]*Bt[n][k] ------------
// MODE 0: + bias[n] ; MODE 1: * dinv[i]
template<int MODE>
__global__ __launch_bounds__(256) void dgemm_kernel(const float* __restrict__ A, const float* __restrict__ Bt,
                                                    int N, int K,
                                                    const float* __restrict__ bias, const float* __restrict__ dinv,
                                                    float* __restrict__ out){
  int g = blockIdx.x*256 + threadIdx.x;   // M*N threads
  int n = g % N;
  int i = g / N;
  const float* a = A  + (size_t)i*K;
  const float* b = Bt + (size_t)n*K;
  float acc = 0.f;
#pragma unroll 8
  for (int k = 0; k < K; ++k) acc = fmaf(a[k], b[k], acc);
  out[g] = (MODE == 0) ? (acc + bias[n]) : (acc * dinv[i]);
}

// --------------- literal aggregation: y_i = sum_k union[i][k] * zs[k] -------
// zs[j][f] = dinv[j] * (h @ Wg)[j][f]
// o = dinv[i]*(y + zs[i]) + bias ; xn = h + wgt * act(o)
template<int F>
__global__ __launch_bounds__(256) void aggd_kernel(const float* __restrict__ zs, const float* __restrict__ h,
                                                   const float* __restrict__ uni,
                                                   const float* __restrict__ bias, const float* __restrict__ dinv,
                                                   float wgt, int doRelu,
                                                   float* __restrict__ outF, float* __restrict__ outD){
  int g = blockIdx.x*256 + threadIdx.x;   // 2048*F
  int f = g & (F - 1);
  int i = g / F;
  const float* ur = uni + (size_t)i*NN;
  float y = 0.f;
#pragma unroll 4
  for (int k = 0; k < NN; ++k) y = fmaf(ur[k], zs[(size_t)k*F + f], y);
  float o = dinv[i]*(y + zs[(size_t)i*F + f]) + bias[f];
  if (doRelu) o = fmaxf(o, 0.f);
  float xn = h[g] + wgt*o;
  outF[g] = xn;
  if (outD) outD[g] = xn;    // final stage: f32 into d_out
}

// --------------- weight transpose + padding, all f32 ------------------------
struct PrepArgs {
  const void *wl1,*bl1,*wl2,*bl2,*wl3,*bl3,*wg1,*bg1,*wg2,*bg2,*wg3,*bg3,*wg4,*bg4,*wg5,*bg5,*wg6,*bg6;
  float *tl1,*tg1,*tl2,*tg2,*tl3,*tg3,*tg4,*tg5,*tg6;
  float *obl1,*obg1,*obl2,*obg2,*obl3,*obg3,*obg4,*obg5,*obg6;
  const int* flag;
};

__global__ __launch_bounds__(256) void prep_kernel(PrepArgs a){
  int bf = *a.flag;
  int t = blockIdx.x*256 + threadIdx.x;     // 131072 threads
  if (t < 256*512){ int n = t>>9, k = t&511; a.tl1[t] = ldf(a.wl1, (size_t)k*256 + n, bf); }
  if (t < 256*256){ int n = t>>8, k = t&255; a.tg1[t] = ldf(a.wg1, (size_t)k*256 + n, bf); }
  if (t <  64*256){ int n = t>>8, k = t&255; a.tl2[t] = (n < 62) ? ldf(a.wl2, (size_t)k*62 + n, bf) : 0.f; }
  if (t <  64*64){
    int n = t>>6, k = t&63;
    a.tg2[t] = (n < 62 && k < 62) ? ldf(a.wg2, (size_t)k*62 + n, bf) : 0.f;
    a.tl3[t] = (k < 62) ? ldf(a.wl3, (size_t)k*64 + n, bf) : 0.f;
    a.tg3[t] = ldf(a.wg3, (size_t)k*64 + n, bf);
    a.tg4[t] = ldf(a.wg4, (size_t)k*64 + n, bf);
    a.tg5[t] = ldf(a.wg5, (size_t)k*64 + n, bf);
    a.tg6[t] = ldf(a.wg6, (size_t)k*64 + n, bf);
  }
  if (t < 256){ a.obl1[t] = ldf(a.bl1, t, bf); a.obg1[t] = ldf(a.bg1, t, bf); }
  if (t < 64){
    a.obl2[t] = (t < 62) ? ldf(a.bl2, t, bf) : 0.f;
    a.obg2[t] = (t < 62) ? ldf(a.bg2, t, bf) : 0.f;
    a.obl3[t] = ldf(a.bl3, t, bf);
    a.obg3[t] = ldf(a.bg3, t, bf);
    a.obg4[t] = ldf(a.bg4, t, bf);
    a.obg5[t] = ldf(a.bg5, t, bf);
    a.obg6[t] = ldf(a.bg6, t, bf);
  }
}

static inline char* wso(void* ws, size_t& off, size_t bytes){
  char* p = (char*)ws + off;
  off += (bytes + 255) & ~(size_t)255;
  return p;
}

extern "C" void kernel_launch(void* const* d_in, const int* in_sizes, int n_in,
                              void* d_out, int out_size, void* d_ws, size_t ws_size,
                              hipStream_t stream){
  // ---- diagnostic checks (all passed in R4; kept as regression guards) ----
  static const int EXP_SIZES[21] = {
    2048*512, 2048*2048, 2048*2048,
    512*256, 256, 256*62, 62, 62*64, 64,
    256*256, 256, 62*62, 62, 64*64, 64,
    64*64, 64, 64*64, 64, 64*64, 64
  };
  float sentinel = 0.f;
  if (n_in != 21) sentinel = 8800000.f;
  if (sentinel == 0.f){
    for (int i = 0; i < 21; ++i)
      if (in_sizes[i] != EXP_SIZES[i]){ sentinel = 100000.f*(float)(i+1); break; }
  }
  if (sentinel == 0.f && out_size != 2048*64) sentinel = 6600000.f;

  // ---- workspace layout ----
  size_t off = 0;
  int*   dflag = (int*)  wso(d_ws, off, 256);
  float* Apb   = (float*)wso(d_ws, off, (size_t)NN*NN*4);
  float* lastB = (float*)wso(d_ws, off, (size_t)NN*NN*4);
  float* newB  = (float*)wso(d_ws, off, (size_t)NN*NN*4);
  float* uniB  = (float*)wso(d_ws, off, (size_t)NN*NN*4);
  float* xf    = (float*)wso(d_ws, off, (size_t)NN*512*4);
  float *tl1 = (float*)wso(d_ws, off, 256*512*4), *tg1 = (float*)wso(d_ws, off, 256*256*4);
  float *tl2 = (float*)wso(d_ws, off,  64*256*4), *tg2 = (float*)wso(d_ws, off,  64*64*4);
  float *tl3 = (float*)wso(d_ws, off,   64*64*4), *tg3 = (float*)wso(d_ws, off,  64*64*4);
  float *tg4 = (float*)wso(d_ws, off,   64*64*4), *tg5 = (float*)wso(d_ws, off,  64*64*4);
  float *tg6 = (float*)wso(d_ws, off,   64*64*4);
  float *obl1 = (float*)wso(d_ws, off, 256*4), *obg1 = (float*)wso(d_ws, off, 256*4);
  float *obl2 = (float*)wso(d_ws, off, 64*4),  *obg2 = (float*)wso(d_ws, off, 64*4);
  float *obl3 = (float*)wso(d_ws, off, 64*4),  *obg3 = (float*)wso(d_ws, off, 64*4);
  float *obg4 = (float*)wso(d_ws, off, 64*4),  *obg5 = (float*)wso(d_ws, off, 64*4);
  float *obg6 = (float*)wso(d_ws, off, 64*4);
  float* dinv = (float*)wso(d_ws, off, NN*4);
  float* hF   = (float*)wso(d_ws, off, (size_t)NN*256*4);
  float* zs   = (float*)wso(d_ws, off, (size_t)NN*256*4);
  float* xF   = (float*)wso(d_ws, off, (size_t)NN*256*4);

  if (sentinel == 0.f && off > ws_size) sentinel = 7700000.f;

  if (sentinel != 0.f){
    sentinel_kernel<<<(NN*64 + 255)/256, 256, 0, stream>>>((float*)d_out, sentinel);
    return;
  }

  const void* x_in = d_in[0];
  const void* An   = d_in[1];
  const void* Ap   = d_in[2];

  probe_kernel<<<1, 256, 0, stream>>>((const u32*)Ap, dflag);
  binz_kernel<<<(NN*NN)/256, 256, 0, stream>>>(An, Ap, lastB, uniB, Apb, dflag);
  convx_kernel<<<(NN*512)/256, 256, 0, stream>>>(x_in, xf, dflag);

  PrepArgs pa;
  pa.wl1=d_in[3];  pa.bl1=d_in[4];
  pa.wl2=d_in[5];  pa.bl2=d_in[6];
  pa.wl3=d_in[7];  pa.bl3=d_in[8];
  pa.wg1=d_in[9];  pa.bg1=d_in[10];
  pa.wg2=d_in[11]; pa.bg2=d_in[12];
  pa.wg3=d_in[13]; pa.bg3=d_in[14];
  pa.wg4=d_in[15]; pa.bg4=d_in[16];
  pa.wg5=d_in[17]; pa.bg5=d_in[18];
  pa.wg6=d_in[19]; pa.bg6=d_in[20];
  pa.tl1=tl1; pa.tg1=tg1; pa.tl2=tl2; pa.tg2=tg2; pa.tl3=tl3;
  pa.tg3=tg3; pa.tg4=tg4; pa.tg5=tg5; pa.tg6=tg6;
  pa.obl1=obl1; pa.obg1=obg1; pa.obl2=obl2; pa.obg2=obg2; pa.obl3=obl3;
  pa.obg3=obg3; pa.obg4=obg4; pa.obg5=obg5; pa.obg6=obg6;
  pa.flag = dflag;
  prep_kernel<<<512, 256, 0, stream>>>(pa);

  float *src = lastB, *dst = newB;
  const float wgts[6]  = {1.f, 1.f, 0.5f, 0.5f, 0.25f, 0.25f};
  const int   relus[6] = {1, 1, 1, 1, 1, 0};

  for (int s = 0; s < 6; ++s){
    if (s > 0){
      expandf_kernel<<<(NN*NN)/256, 256, 0, stream>>>(src, Apb, dst, uniB);
      float* t = src; src = dst; dst = t;
    }
    degk_kernel<<<NN, 256, 0, stream>>>(uniB, dinv);

    if (s == 0){
      dgemm_kernel<0><<<(NN*256)/256, 256, 0, stream>>>(xf, tl1, 256, 512, obl1, nullptr, hF);
      dgemm_kernel<1><<<(NN*256)/256, 256, 0, stream>>>(hF, tg1, 256, 256, nullptr, dinv, zs);
      aggd_kernel<256><<<(NN*256)/256, 256, 0, stream>>>(zs, hF, uniB, obg1, dinv, wgts[0], relus[0], xF, nullptr);
    } else if (s == 1){
      dgemm_kernel<0><<<(NN*64)/256, 256, 0, stream>>>(xF, tl2, 64, 256, obl2, nullptr, hF);
      dgemm_kernel<1><<<(NN*64)/256, 256, 0, stream>>>(hF, tg2, 64, 64, nullptr, dinv, zs);
      aggd_kernel<64><<<(NN*64)/256, 256, 0, stream>>>(zs, hF, uniB, obg2, dinv, wgts[1], relus[1], xF, nullptr);
    } else if (s == 2){
      dgemm_kernel<0><<<(NN*64)/256, 256, 0, stream>>>(xF, tl3, 64, 64, obl3, nullptr, hF);
      dgemm_kernel<1><<<(NN*64)/256, 256, 0, stream>>>(hF, tg3, 64, 64, nullptr, dinv, zs);
      aggd_kernel<64><<<(NN*64)/256, 256, 0, stream>>>(zs, hF, uniB, obg3, dinv, wgts[2], relus[2], xF, nullptr);
    } else {
      const float* tg = (s == 3) ? tg4 : (s == 4) ? tg5 : tg6;
      const float* ob = (s == 3) ? obg4 : (s == 4) ? obg5 : obg6;
      dgemm_kernel<1><<<(NN*64)/256, 256, 0, stream>>>(xF, tg, 64, 64, nullptr, dinv, zs);
      float* outD = (s == 5) ? (float*)d_out : nullptr;
      aggd_kernel<64><<<(NN*64)/256, 256, 0, stream>>>(zs, xF, uniB, ob, dinv, wgts[s], relus[s], xF, outD);
    }
  }
}

// Round 7
// 1465.005 us; speedup vs baseline: 7.1592x; 7.1592x over previous
//
#include <hip/hip_runtime.h>

typedef unsigned short u16;
typedef unsigned int   u32;
typedef unsigned long long u64;

#define NN 2048

__device__ __forceinline__ float b2f(u16 u){ union { u32 i; float f; } x; x.i = ((u32)u)<<16; return x.f; }
// dtype-adaptive load: bf==1 -> bf16 storage, bf==0 -> fp32 storage
__device__ __forceinline__ float ldf(const void* p, size_t i, int bf){
  return bf ? b2f(((const u16*)p)[i]) : ((const float*)p)[i];
}

// ---------------- diagnostic sentinel (f32 out) ------------------------------
__global__ __launch_bounds__(256) void sentinel_kernel(float* __restrict__ out, float val){
  int g = blockIdx.x*256 + threadIdx.x;
  if (g < NN*64) out[g] = val;
}

// ---------------- dtype probe: fp32 A_pos words are exactly 0 / 0x3F800000 --
__global__ __launch_bounds__(256) void probe_kernel(const u32* __restrict__ ap, int* __restrict__ flag){
  __shared__ int sb[256];
  int bad = 0;
  for (int i = threadIdx.x; i < 65536; i += 256){
    u32 w = ap[i];
    if (w != 0u && w != 0x3F800000u) bad++;
  }
  sb[threadIdx.x] = bad;
  __syncthreads();
  if (threadIdx.x == 0){
    int t = 0;
    for (int k = 0; k < 256; ++k) t += sb[k];
    *flag = (t > 0) ? 1 : 0;
  }
}

// ---------------- x -> f32 ---------------------------------------------------
__global__ __launch_bounds__(256) void convx_kernel(const void* __restrict__ x, float* __restrict__ xf,
                                                    const int* __restrict__ flag){
  int bf = *flag;
  size_t i = (size_t)blockIdx.x*256 + threadIdx.x;   // 2048*512
  xf[i] = ldf(x, i, bf);
}

// ---------------- CSC of A_pos (per-column nnz lists, cap 64) ----------------
__global__ __launch_bounds__(256) void csc_kernel(const void* __restrict__ Ap,
                                                  int* __restrict__ cnt, int* __restrict__ idx,
                                                  const int* __restrict__ flag){
  int bf = *flag;
  size_t e = (size_t)blockIdx.x*256 + threadIdx.x;   // 2048*2048 elements, e = k*2048 + j
  int k = (int)(e >> 11), j = (int)(e & 2047);
  if (ldf(Ap, e, bf) > 0.f){
    int p = atomicAdd(&cnt[j], 1);
    if (p < 64) idx[j*64 + p] = k;
  }
}

// --------------- column bitsets of A_neg: last/union init --------------------
// col bitset j, word w: bit b = A_neg[w*64+b][j]
__global__ __launch_bounds__(256) void negbits_kernel(const void* __restrict__ An,
                                                      u64* __restrict__ last, u64* __restrict__ uni,
                                                      const int* __restrict__ flag){
  int bf = *flag;
  int g = blockIdx.x*256 + threadIdx.x;   // 65536 = 2048 cols * 32 words
  int j = g & 2047, w = g >> 11;
  u64 bits = 0;
  for (int b = 0; b < 64; ++b){
    float v = ldf(An, (size_t)(w*64 + b)*NN + j, bf);
    bits |= (u64)(v > 0.f) << b;
  }
  last[(size_t)j*32 + w] = bits;
  uni [(size_t)j*32 + w] = bits;
}

// --------------- expansion: new_col[j] = OR_{k in Ap[:,j]} last_col[k] ------
__global__ __launch_bounds__(256) void expand_kernel(const u64* __restrict__ src, u64* __restrict__ dst,
                                                     u64* __restrict__ uni,
                                                     const int* __restrict__ cnt, const int* __restrict__ idx){
  int g = blockIdx.x*256 + threadIdx.x;   // 65536
  int w = g & 31, j = g >> 5;
  int c = cnt[j]; c = (c > 64) ? 64 : c;
  const int* lst = idx + j*64;
  u64 acc = 0;
  for (int t = 0; t < c; ++t) acc |= src[(size_t)lst[t]*32 + w];
  dst[(size_t)j*32 + w] = acc;
  uni[(size_t)j*32 + w] |= acc;
}

// --------------- 64x64 bit transpose: col bitsets -> row bitsets ------------
__global__ __launch_bounds__(64) void bittrans_kernel(const u64* __restrict__ colb, u64* __restrict__ rowb){
  __shared__ u64 lds[64];
  int wi = blockIdx.x, wj = blockIdx.y;
  int t = threadIdx.x;
  lds[t] = colb[(size_t)(wj*64 + t)*32 + wi];
  __syncthreads();
  u64 out = 0;
#pragma unroll
  for (int tt = 0; tt < 64; ++tt) out |= ((lds[tt] >> t) & 1ULL) << tt;
  rowb[(size_t)(wi*64 + t)*32 + wj] = out;
}

// --------------- row degrees -> dinv + complement-mode flag ------------------
__global__ __launch_bounds__(256) void degb_kernel(const u64* __restrict__ rowb,
                                                   float* __restrict__ dinv, int* __restrict__ mrow){
  int i = blockIdx.x*256 + threadIdx.x;   // 2048
  int t = 0;
  for (int w = 0; w < 32; ++w) t += __popcll(rowb[(size_t)i*32 + w]);
  dinv[i] = 1.0f / sqrtf((float)(t + 1));
  mrow[i] = (t > 1024) ? 1 : 0;
}

// --------------- dumb f32 GEMM: C[i][n] = sum_k A[i][k]*Bt[n][k] ------------
// MODE 0: + bias[n] ; MODE 1: * dinv[i]   (verbatim from passing R6)
template<int MODE>
__global__ __launch_bounds__(256) void dgemm_kernel(const float* __restrict__ A, const float* __restrict__ Bt,
                                                    int N, int K,
                                                    const float* __restrict__ bias, const float* __restrict__ dinv,
                                                    float* __restrict__ out){
  int g = blockIdx.x*256 + threadIdx.x;   // M*N threads
  int n = g % N;
  int i = g / N;
  const float* a = A  + (size_t)i*K;
  const float* b = Bt + (size_t)n*K;
  float acc = 0.f;
#pragma unroll 8
  for (int k = 0; k < K; ++k) acc = fmaf(a[k], b[k], acc);
  out[g] = (MODE == 0) ? (acc + bias[n]) : (acc * dinv[i]);
}

// --------------- column sums of zs (for complement-mode rows) ----------------
__global__ __launch_bounds__(256) void colsumf_kernel(const float* __restrict__ zs, int F,
                                                      float* __restrict__ out){
  __shared__ float sd[4][64];
  int f0 = blockIdx.x*64;
  int f = threadIdx.x & 63, g = threadIdx.x >> 6;
  float s = 0.f;
  for (int i = g; i < NN; i += 4) s += zs[(size_t)i*F + f0 + f];
  sd[g][f] = s;
  __syncthreads();
  if (threadIdx.x < 64) out[f0 + f] = sd[0][f] + sd[1][f] + sd[2][f] + sd[3][f];
}

// --------------- aggregation via rowbit scan (+complement for dense rows) ---
// zs[j][f] = dinv[j]*(h @ Wg)[j][f]
// y_i = sum_{k in union_i} zs[k]  (mode: colsum - sum over ~bits)
// o = dinv[i]*(y + zs[i]) + bias ; xn = h + wgt*act(o)
template<int F>
__global__ __launch_bounds__(256) void aggb_kernel(const float* __restrict__ zs, const float* __restrict__ h,
                                                   const u64* __restrict__ rowb,
                                                   const float* __restrict__ colsum,
                                                   const float* __restrict__ bias, const float* __restrict__ dinv,
                                                   const int* __restrict__ mrow,
                                                   float wgt, int doRelu,
                                                   float* __restrict__ outF, float* __restrict__ outD){
  int i, f;
  if (F == 256){ i = blockIdx.x;                        f = threadIdx.x;      }
  else         { i = blockIdx.x*4 + (threadIdx.x >> 6); f = threadIdx.x & 63; }
  const u64* rb = rowb + (size_t)i*32;
  int mode = mrow[i];
  float s = 0.f;
  for (int w = 0; w < 32; ++w){
    u64 bits = rb[w];
    if (mode) bits = ~bits;
    int base = w*64;
    while (bits){
      int b = __ffsll((unsigned long long)bits) - 1;
      s += zs[(size_t)(base + b)*F + f];
      bits &= bits - 1;
    }
  }
  float y = mode ? (colsum[f] - s) : s;
  float o = dinv[i]*(y + zs[(size_t)i*F + f]) + bias[f];
  if (doRelu) o = fmaxf(o, 0.f);
  float xn = h[(size_t)i*F + f] + wgt*o;
  outF[(size_t)i*F + f] = xn;
  if (outD) outD[(size_t)i*F + f] = xn;
}

// --------------- weight transpose + padding, all f32 (verbatim R6) ----------
struct PrepArgs {
  const void *wl1,*bl1,*wl2,*bl2,*wl3,*bl3,*wg1,*bg1,*wg2,*bg2,*wg3,*bg3,*wg4,*bg4,*wg5,*bg5,*wg6,*bg6;
  float *tl1,*tg1,*tl2,*tg2,*tl3,*tg3,*tg4,*tg5,*tg6;
  float *obl1,*obg1,*obl2,*obg2,*obl3,*obg3,*obg4,*obg5,*obg6;
  const int* flag;
};

__global__ __launch_bounds__(256) void prep_kernel(PrepArgs a){
  int bf = *a.flag;
  int t = blockIdx.x*256 + threadIdx.x;     // 131072 threads
  if (t < 256*512){ int n = t>>9, k = t&511; a.tl1[t] = ldf(a.wl1, (size_t)k*256 + n, bf); }
  if (t < 256*256){ int n = t>>8, k = t&255; a.tg1[t] = ldf(a.wg1, (size_t)k*256 + n, bf); }
  if (t <  64*256){ int n = t>>8, k = t&255; a.tl2[t] = (n < 62) ? ldf(a.wl2, (size_t)k*62 + n, bf) : 0.f; }
  if (t <  64*64){
    int n = t>>6, k = t&63;
    a.tg2[t] = (n < 62 && k < 62) ? ldf(a.wg2, (size_t)k*62 + n, bf) : 0.f;
    a.tl3[t] = (k < 62) ? ldf(a.wl3, (size_t)k*64 + n, bf) : 0.f;
    a.tg3[t] = ldf(a.wg3, (size_t)k*64 + n, bf);
    a.tg4[t] = ldf(a.wg4, (size_t)k*64 + n, bf);
    a.tg5[t] = ldf(a.wg5, (size_t)k*64 + n, bf);
    a.tg6[t] = ldf(a.wg6, (size_t)k*64 + n, bf);
  }
  if (t < 256){ a.obl1[t] = ldf(a.bl1, t, bf); a.obg1[t] = ldf(a.bg1, t, bf); }
  if (t < 64){
    a.obl2[t] = (t < 62) ? ldf(a.bl2, t, bf) : 0.f;
    a.obg2[t] = (t < 62) ? ldf(a.bg2, t, bf) : 0.f;
    a.obl3[t] = ldf(a.bl3, t, bf);
    a.obg3[t] = ldf(a.bg3, t, bf);
    a.obg4[t] = ldf(a.bg4, t, bf);
    a.obg5[t] = ldf(a.bg5, t, bf);
    a.obg6[t] = ldf(a.bg6, t, bf);
  }
}

static inline char* wso(void* ws, size_t& off, size_t bytes){
  char* p = (char*)ws + off;
  off += (bytes + 255) & ~(size_t)255;
  return p;
}

extern "C" void kernel_launch(void* const* d_in, const int* in_sizes, int n_in,
                              void* d_out, int out_size, void* d_ws, size_t ws_size,
                              hipStream_t stream){
  // ---- regression guards (validated in R4-R6) ----
  static const int EXP_SIZES[21] = {
    2048*512, 2048*2048, 2048*2048,
    512*256, 256, 256*62, 62, 62*64, 64,
    256*256, 256, 62*62, 62, 64*64, 64,
    64*64, 64, 64*64, 64, 64*64, 64
  };
  float sentinel = 0.f;
  if (n_in != 21) sentinel = 8800000.f;
  if (sentinel == 0.f){
    for (int i = 0; i < 21; ++i)
      if (in_sizes[i] != EXP_SIZES[i]){ sentinel = 100000.f*(float)(i+1); break; }
  }
  if (sentinel == 0.f && out_size != 2048*64) sentinel = 6600000.f;

  // ---- workspace layout ----
  size_t off = 0;
  int*   dflag  = (int*)  wso(d_ws, off, 256);
  int*   ap_cnt = (int*)  wso(d_ws, off, NN*4);
  int*   ap_idx = (int*)  wso(d_ws, off, NN*64*4);
  u64*   colA   = (u64*)  wso(d_ws, off, (size_t)NN*32*8);
  u64*   colB   = (u64*)  wso(d_ws, off, (size_t)NN*32*8);
  u64*   colU   = (u64*)  wso(d_ws, off, (size_t)NN*32*8);
  u64*   rowb   = (u64*)  wso(d_ws, off, (size_t)NN*32*8);
  float* dinv   = (float*)wso(d_ws, off, NN*4);
  int*   mrow   = (int*)  wso(d_ws, off, NN*4);
  float* csum   = (float*)wso(d_ws, off, 256*4);
  float* xf     = (float*)wso(d_ws, off, (size_t)NN*512*4);
  float *tl1 = (float*)wso(d_ws, off, 256*512*4), *tg1 = (float*)wso(d_ws, off, 256*256*4);
  float *tl2 = (float*)wso(d_ws, off,  64*256*4), *tg2 = (float*)wso(d_ws, off,  64*64*4);
  float *tl3 = (float*)wso(d_ws, off,   64*64*4), *tg3 = (float*)wso(d_ws, off,  64*64*4);
  float *tg4 = (float*)wso(d_ws, off,   64*64*4), *tg5 = (float*)wso(d_ws, off,  64*64*4);
  float *tg6 = (float*)wso(d_ws, off,   64*64*4);
  float *obl1 = (float*)wso(d_ws, off, 256*4), *obg1 = (float*)wso(d_ws, off, 256*4);
  float *obl2 = (float*)wso(d_ws, off, 64*4),  *obg2 = (float*)wso(d_ws, off, 64*4);
  float *obl3 = (float*)wso(d_ws, off, 64*4),  *obg3 = (float*)wso(d_ws, off, 64*4);
  float *obg4 = (float*)wso(d_ws, off, 64*4),  *obg5 = (float*)wso(d_ws, off, 64*4);
  float *obg6 = (float*)wso(d_ws, off, 64*4);
  float* hF   = (float*)wso(d_ws, off, (size_t)NN*256*4);
  float* zs   = (float*)wso(d_ws, off, (size_t)NN*256*4);
  float* xF   = (float*)wso(d_ws, off, (size_t)NN*256*4);

  if (sentinel == 0.f && off > ws_size) sentinel = 7700000.f;

  if (sentinel != 0.f){
    sentinel_kernel<<<(NN*64 + 255)/256, 256, 0, stream>>>((float*)d_out, sentinel);
    return;
  }

  const void* x_in = d_in[0];
  const void* An   = d_in[1];
  const void* Ap   = d_in[2];

  probe_kernel<<<1, 256, 0, stream>>>((const u32*)Ap, dflag);
  hipMemsetAsync(ap_cnt, 0, NN*sizeof(int), stream);
  csc_kernel<<<(NN*NN)/256, 256, 0, stream>>>(Ap, ap_cnt, ap_idx, dflag);
  negbits_kernel<<<(NN*32)/256, 256, 0, stream>>>(An, colA, colU, dflag);
  convx_kernel<<<(NN*512)/256, 256, 0, stream>>>(x_in, xf, dflag);

  PrepArgs pa;
  pa.wl1=d_in[3];  pa.bl1=d_in[4];
  pa.wl2=d_in[5];  pa.bl2=d_in[6];
  pa.wl3=d_in[7];  pa.bl3=d_in[8];
  pa.wg1=d_in[9];  pa.bg1=d_in[10];
  pa.wg2=d_in[11]; pa.bg2=d_in[12];
  pa.wg3=d_in[13]; pa.bg3=d_in[14];
  pa.wg4=d_in[15]; pa.bg4=d_in[16];
  pa.wg5=d_in[17]; pa.bg5=d_in[18];
  pa.wg6=d_in[19]; pa.bg6=d_in[20];
  pa.tl1=tl1; pa.tg1=tg1; pa.tl2=tl2; pa.tg2=tg2; pa.tl3=tl3;
  pa.tg3=tg3; pa.tg4=tg4; pa.tg5=tg5; pa.tg6=tg6;
  pa.obl1=obl1; pa.obg1=obg1; pa.obl2=obl2; pa.obg2=obg2; pa.obl3=obl3;
  pa.obg3=obg3; pa.obg4=obg4; pa.obg5=obg5; pa.obg6=obg6;
  pa.flag = dflag;
  prep_kernel<<<512, 256, 0, stream>>>(pa);

  u64 *src = colA, *dst = colB;
  const float wgts[6]  = {1.f, 1.f, 0.5f, 0.5f, 0.25f, 0.25f};
  const int   relus[6] = {1, 1, 1, 1, 1, 0};

  for (int s = 0; s < 6; ++s){
    if (s > 0){
      expand_kernel<<<(NN*32)/256, 256, 0, stream>>>(src, dst, colU, ap_cnt, ap_idx);
      u64* t = src; src = dst; dst = t;
    }
    bittrans_kernel<<<dim3(32,32), 64, 0, stream>>>(colU, rowb);
    degb_kernel<<<NN/256, 256, 0, stream>>>(rowb, dinv, mrow);

    if (s == 0){
      dgemm_kernel<0><<<(NN*256)/256, 256, 0, stream>>>(xf, tl1, 256, 512, obl1, nullptr, hF);
      dgemm_kernel<1><<<(NN*256)/256, 256, 0, stream>>>(hF, tg1, 256, 256, nullptr, dinv, zs);
      colsumf_kernel<<<4, 256, 0, stream>>>(zs, 256, csum);
      aggb_kernel<256><<<NN, 256, 0, stream>>>(zs, hF, rowb, csum, obg1, dinv, mrow,
                                               wgts[0], relus[0], xF, nullptr);
    } else if (s == 1){
      dgemm_kernel<0><<<(NN*64)/256, 256, 0, stream>>>(xF, tl2, 64, 256, obl2, nullptr, hF);
      dgemm_kernel<1><<<(NN*64)/256, 256, 0, stream>>>(hF, tg2, 64, 64, nullptr, dinv, zs);
      colsumf_kernel<<<1, 256, 0, stream>>>(zs, 64, csum);
      aggb_kernel<64><<<NN/4, 256, 0, stream>>>(zs, hF, rowb, csum, obg2, dinv, mrow,
                                                wgts[1], relus[1], xF, nullptr);
    } else if (s == 2){
      dgemm_kernel<0><<<(NN*64)/256, 256, 0, stream>>>(xF, tl3, 64, 64, obl3, nullptr, hF);
      dgemm_kernel<1><<<(NN*64)/256, 256, 0, stream>>>(hF, tg3, 64, 64, nullptr, dinv, zs);
      colsumf_kernel<<<1, 256, 0, stream>>>(zs, 64, csum);
      aggb_kernel<64><<<NN/4, 256, 0, stream>>>(zs, hF, rowb, csum, obg3, dinv, mrow,
                                                wgts[2], relus[2], xF, nullptr);
    } else {
      const float* tg = (s == 3) ? tg4 : (s == 4) ? tg5 : tg6;
      const float* ob = (s == 3) ? obg4 : (s == 4) ? obg5 : obg6;
      dgemm_kernel<1><<<(NN*64)/256, 256, 0, stream>>>(xF, tg, 64, 64, nullptr, dinv, zs);
      colsumf_kernel<<<1, 256, 0, stream>>>(zs, 64, csum);
      float* outD = (s == 5) ? (float*)d_out : nullptr;
      aggb_kernel<64><<<NN/4, 256, 0, stream>>>(zs, xF, rowb, csum, ob, dinv, mrow,
                                                wgts[s], relus[s], xF, outD);
    }
  }
}

// Round 8
// 1237.066 us; speedup vs baseline: 8.4784x; 1.1843x over previous
//
#include <hip/hip_runtime.h>

typedef unsigned short u16;
typedef unsigned int   u32;
typedef unsigned long long u64;
typedef __attribute__((ext_vector_type(8))) short short8;
typedef __attribute__((ext_vector_type(4))) float f32x4;

#define NN 2048

__device__ __forceinline__ float b2f(u16 u){ union { u32 i; float f; } x; x.i = ((u32)u)<<16; return x.f; }
__device__ __forceinline__ u16 f2b(float f){
  u32 u = __float_as_uint(f);
  u32 r = (u + 0x7fffu + ((u>>16)&1u)) >> 16;
  return (u16)r;
}
// dtype-adaptive load: bf==1 -> bf16 storage, bf==0 -> fp32 storage
__device__ __forceinline__ float ldf(const void* p, size_t i, int bf){
  return bf ? b2f(((const u16*)p)[i]) : ((const float*)p)[i];
}
// split f32 into hi+lo bf16 (3-pass MFMA gives ~2^-18 relative accuracy)
__device__ __forceinline__ void splitbf(float v, u16& h, u16& l){
  h = f2b(v);
  l = f2b(v - b2f(h));
}

// ---------------- diagnostic sentinel (f32 out) ------------------------------
__global__ __launch_bounds__(256) void sentinel_kernel(float* __restrict__ out, float val){
  int g = blockIdx.x*256 + threadIdx.x;
  if (g < NN*64) out[g] = val;
}

// ---------------- dtype probe: fp32 A_pos words are exactly 0 / 0x3F800000 --
__global__ __launch_bounds__(256) void probe_kernel(const u32* __restrict__ ap, int* __restrict__ flag){
  __shared__ int sb[256];
  int bad = 0;
  for (int i = threadIdx.x; i < 65536; i += 256){
    u32 w = ap[i];
    if (w != 0u && w != 0x3F800000u) bad++;
  }
  sb[threadIdx.x] = bad;
  __syncthreads();
  if (threadIdx.x == 0){
    int t = 0;
    for (int k = 0; k < 256; ++k) t += sb[k];
    *flag = (t > 0) ? 1 : 0;
  }
}

// ---------------- x -> f32 ---------------------------------------------------
__global__ __launch_bounds__(256) void convx_kernel(const void* __restrict__ x, float* __restrict__ xf,
                                                    const int* __restrict__ flag){
  int bf = *flag;
  size_t i = (size_t)blockIdx.x*256 + threadIdx.x;   // 2048*512
  xf[i] = ldf(x, i, bf);
}

// ---------------- CSC of A_pos (per-column nnz lists, cap 64) ----------------
__global__ __launch_bounds__(256) void csc_kernel(const void* __restrict__ Ap,
                                                  int* __restrict__ cnt, int* __restrict__ idx,
                                                  const int* __restrict__ flag){
  int bf = *flag;
  size_t e = (size_t)blockIdx.x*256 + threadIdx.x;   // 2048*2048 elements, e = k*2048 + j
  int k = (int)(e >> 11), j = (int)(e & 2047);
  if (ldf(Ap, e, bf) > 0.f){
    int p = atomicAdd(&cnt[j], 1);
    if (p < 64) idx[j*64 + p] = k;
  }
}

// --------------- column bitsets of A_neg: last/union init --------------------
__global__ __launch_bounds__(256) void negbits_kernel(const void* __restrict__ An,
                                                      u64* __restrict__ last, u64* __restrict__ uni,
                                                      const int* __restrict__ flag){
  int bf = *flag;
  int g = blockIdx.x*256 + threadIdx.x;   // 65536 = 2048 cols * 32 words
  int j = g & 2047, w = g >> 11;
  u64 bits = 0;
  for (int b = 0; b < 64; ++b){
    float v = ldf(An, (size_t)(w*64 + b)*NN + j, bf);
    bits |= (u64)(v > 0.f) << b;
  }
  last[(size_t)j*32 + w] = bits;
  uni [(size_t)j*32 + w] = bits;
}

// --------------- expansion: new_col[j] = OR_{k in Ap[:,j]} last_col[k] ------
__global__ __launch_bounds__(256) void expand_kernel(const u64* __restrict__ src, u64* __restrict__ dst,
                                                     u64* __restrict__ uni,
                                                     const int* __restrict__ cnt, const int* __restrict__ idx){
  int g = blockIdx.x*256 + threadIdx.x;   // 65536
  int w = g & 31, j = g >> 5;
  int c = cnt[j]; c = (c > 64) ? 64 : c;
  const int* lst = idx + j*64;
  u64 acc = 0;
  for (int t = 0; t < c; ++t) acc |= src[(size_t)lst[t]*32 + w];
  dst[(size_t)j*32 + w] = acc;
  uni[(size_t)j*32 + w] |= acc;
}

// --------------- 64x64 bit transpose: col bitsets -> row bitsets ------------
__global__ __launch_bounds__(64) void bittrans_kernel(const u64* __restrict__ colb, u64* __restrict__ rowb){
  __shared__ u64 lds[64];
  int wi = blockIdx.x, wj = blockIdx.y;
  int t = threadIdx.x;
  lds[t] = colb[(size_t)(wj*64 + t)*32 + wi];
  __syncthreads();
  u64 out = 0;
#pragma unroll
  for (int tt = 0; tt < 64; ++tt) out |= ((lds[tt] >> t) & 1ULL) << tt;
  rowb[(size_t)(wi*64 + t)*32 + wj] = out;
}

// --------------- row degrees -> dinv + complement-mode flag ------------------
__global__ __launch_bounds__(256) void degb_kernel(const u64* __restrict__ rowb,
                                                   float* __restrict__ dinv, int* __restrict__ mrow){
  int i = blockIdx.x*256 + threadIdx.x;   // 2048
  int t = 0;
  for (int w = 0; w < 32; ++w) t += __popcll(rowb[(size_t)i*32 + w]);
  dinv[i] = 1.0f / sqrtf((float)(t + 1));
  mrow[i] = (t > 1024) ? 1 : 0;
}

// --------------- split-bf16 MFMA GEMM: C[i][n] = sum_k A[i][k]*Bt[n][k] -----
// A f32 (M x K), Bt f32 (N x K), K % 64 == 0. 3-pass hi/lo for ~f32 accuracy.
// MODE 0: + bias[n] ; MODE 1: * dinv[i]
template<int MODE>
__global__ __launch_bounds__(256) void mgemm_kernel(const float* __restrict__ A, const float* __restrict__ Bt,
                                                    int N, int K,
                                                    const float* __restrict__ bias, const float* __restrict__ dinv,
                                                    float* __restrict__ outF){
  constexpr int LDT = 72;                 // 64 + 8 pad (16B-aligned rows)
  __shared__ u16 Ah[64*LDT], Al[64*LDT], Bh[64*LDT], Bl[64*LDT];
  const int m0 = blockIdx.x*64, n0 = blockIdx.y*64;
  const int tid = threadIdx.x;
  const int wave = tid >> 6, lane = tid & 63;
  const int wm = (wave>>1)*32, wn = (wave&1)*32;
  const int q = lane >> 4, l16 = lane & 15;
  f32x4 acc00 = {}, acc01 = {}, acc10 = {}, acc11 = {};
  const int sr = tid >> 2, sc = (tid & 3)*16;   // each thread: 16 consecutive floats of one row
  for (int k0 = 0; k0 < K; k0 += 64){
    const float* Ag = A  + (size_t)(m0+sr)*K + k0 + sc;
    const float* Bg = Bt + (size_t)(n0+sr)*K + k0 + sc;
#pragma unroll
    for (int v4 = 0; v4 < 4; ++v4){
      float4 av = ((const float4*)Ag)[v4];
      float4 bv = ((const float4*)Bg)[v4];
      int o = sr*LDT + sc + v4*4;
      splitbf(av.x, Ah[o+0], Al[o+0]); splitbf(av.y, Ah[o+1], Al[o+1]);
      splitbf(av.z, Ah[o+2], Al[o+2]); splitbf(av.w, Ah[o+3], Al[o+3]);
      splitbf(bv.x, Bh[o+0], Bl[o+0]); splitbf(bv.y, Bh[o+1], Bl[o+1]);
      splitbf(bv.z, Bh[o+2], Bl[o+2]); splitbf(bv.w, Bh[o+3], Bl[o+3]);
    }
    __syncthreads();
#pragma unroll
    for (int ks = 0; ks < 2; ++ks){
      const int kb = ks*32 + q*8;
      short8 ah0 = *(const short8*)&Ah[(wm      + l16)*LDT + kb];
      short8 al0 = *(const short8*)&Al[(wm      + l16)*LDT + kb];
      short8 ah1 = *(const short8*)&Ah[(wm + 16 + l16)*LDT + kb];
      short8 al1 = *(const short8*)&Al[(wm + 16 + l16)*LDT + kb];
      short8 bh0 = *(const short8*)&Bh[(wn      + l16)*LDT + kb];
      short8 bl0 = *(const short8*)&Bl[(wn      + l16)*LDT + kb];
      short8 bh1 = *(const short8*)&Bh[(wn + 16 + l16)*LDT + kb];
      short8 bl1 = *(const short8*)&Bl[(wn + 16 + l16)*LDT + kb];
      acc00 = __builtin_amdgcn_mfma_f32_16x16x32_bf16(ah0, bh0, acc00, 0, 0, 0);
      acc00 = __builtin_amdgcn_mfma_f32_16x16x32_bf16(ah0, bl0, acc00, 0, 0, 0);
      acc00 = __builtin_amdgcn_mfma_f32_16x16x32_bf16(al0, bh0, acc00, 0, 0, 0);
      acc01 = __builtin_amdgcn_mfma_f32_16x16x32_bf16(ah0, bh1, acc01, 0, 0, 0);
      acc01 = __builtin_amdgcn_mfma_f32_16x16x32_bf16(ah0, bl1, acc01, 0, 0, 0);
      acc01 = __builtin_amdgcn_mfma_f32_16x16x32_bf16(al0, bh1, acc01, 0, 0, 0);
      acc10 = __builtin_amdgcn_mfma_f32_16x16x32_bf16(ah1, bh0, acc10, 0, 0, 0);
      acc10 = __builtin_amdgcn_mfma_f32_16x16x32_bf16(ah1, bl0, acc10, 0, 0, 0);
      acc10 = __builtin_amdgcn_mfma_f32_16x16x32_bf16(al1, bh0, acc10, 0, 0, 0);
      acc11 = __builtin_amdgcn_mfma_f32_16x16x32_bf16(ah1, bh1, acc11, 0, 0, 0);
      acc11 = __builtin_amdgcn_mfma_f32_16x16x32_bf16(ah1, bl1, acc11, 0, 0, 0);
      acc11 = __builtin_amdgcn_mfma_f32_16x16x32_bf16(al1, bh1, acc11, 0, 0, 0);
    }
    __syncthreads();
  }
#pragma unroll
  for (int mi = 0; mi < 2; ++mi)
#pragma unroll
  for (int ni = 0; ni < 2; ++ni){
    f32x4 a = (mi == 0) ? ((ni == 0) ? acc00 : acc01) : ((ni == 0) ? acc10 : acc11);
#pragma unroll
    for (int r = 0; r < 4; ++r){
      int i = m0 + wm + mi*16 + q*4 + r;      // C/D: row=(lane>>4)*4+reg, col=lane&15
      int n = n0 + wn + ni*16 + l16;
      float v = a[r];
      if constexpr (MODE == 0) v += bias[n];
      else                     v *= dinv[i];
      outF[(size_t)i*N + n] = v;
    }
  }
}

// --------------- column sums of zs (for complement-mode rows) ----------------
__global__ __launch_bounds__(256) void colsumf_kernel(const float* __restrict__ zs, int F,
                                                      float* __restrict__ out){
  __shared__ float sd[4][64];
  int f0 = blockIdx.x*64;
  int f = threadIdx.x & 63, g = threadIdx.x >> 6;
  float s = 0.f;
  for (int i = g; i < NN; i += 4) s += zs[(size_t)i*F + f0 + f];
  sd[g][f] = s;
  __syncthreads();
  if (threadIdx.x < 64) out[f0 + f] = sd[0][f] + sd[1][f] + sd[2][f] + sd[3][f];
}

// --------------- aggregation via rowbit scan (+complement for dense rows) ---
template<int F>
__global__ __launch_bounds__(256) void aggb_kernel(const float* __restrict__ zs, const float* __restrict__ h,
                                                   const u64* __restrict__ rowb,
                                                   const float* __restrict__ colsum,
                                                   const float* __restrict__ bias, const float* __restrict__ dinv,
                                                   const int* __restrict__ mrow,
                                                   float wgt, int doRelu,
                                                   float* __restrict__ outF, float* __restrict__ outD){
  int i, f;
  if (F == 256){ i = blockIdx.x;                        f = threadIdx.x;      }
  else         { i = blockIdx.x*4 + (threadIdx.x >> 6); f = threadIdx.x & 63; }
  const u64* rb = rowb + (size_t)i*32;
  int mode = mrow[i];
  float s = 0.f;
  for (int w = 0; w < 32; ++w){
    u64 bits = rb[w];
    if (mode) bits = ~bits;
    int base = w*64;
    while (bits){
      int b = __ffsll((unsigned long long)bits) - 1;
      s += zs[(size_t)(base + b)*F + f];
      bits &= bits - 1;
    }
  }
  float y = mode ? (colsum[f] - s) : s;
  float o = dinv[i]*(y + zs[(size_t)i*F + f]) + bias[f];
  if (doRelu) o = fmaxf(o, 0.f);
  float xn = h[(size_t)i*F + f] + wgt*o;
  outF[(size_t)i*F + f] = xn;
  if (outD) outD[(size_t)i*F + f] = xn;
}

// --------------- weight transpose + padding, all f32 ------------------------
struct PrepArgs {
  const void *wl1,*bl1,*wl2,*bl2,*wl3,*bl3,*wg1,*bg1,*wg2,*bg2,*wg3,*bg3,*wg4,*bg4,*wg5,*bg5,*wg6,*bg6;
  float *tl1,*tg1,*tl2,*tg2,*tl3,*tg3,*tg4,*tg5,*tg6;
  float *obl1,*obg1,*obl2,*obg2,*obl3,*obg3,*obg4,*obg5,*obg6;
  const int* flag;
};

__global__ __launch_bounds__(256) void prep_kernel(PrepArgs a){
  int bf = *a.flag;
  int t = blockIdx.x*256 + threadIdx.x;     // 131072 threads
  if (t < 256*512){ int n = t>>9, k = t&511; a.tl1[t] = ldf(a.wl1, (size_t)k*256 + n, bf); }
  if (t < 256*256){ int n = t>>8, k = t&255; a.tg1[t] = ldf(a.wg1, (size_t)k*256 + n, bf); }
  if (t <  64*256){ int n = t>>8, k = t&255; a.tl2[t] = (n < 62) ? ldf(a.wl2, (size_t)k*62 + n, bf) : 0.f; }
  if (t <  64*64){
    int n = t>>6, k = t&63;
    a.tg2[t] = (n < 62 && k < 62) ? ldf(a.wg2, (size_t)k*62 + n, bf) : 0.f;
    a.tl3[t] = (k < 62) ? ldf(a.wl3, (size_t)k*64 + n, bf) : 0.f;
    a.tg3[t] = ldf(a.wg3, (size_t)k*64 + n, bf);
    a.tg4[t] = ldf(a.wg4, (size_t)k*64 + n, bf);
    a.tg5[t] = ldf(a.wg5, (size_t)k*64 + n, bf);
    a.tg6[t] = ldf(a.wg6, (size_t)k*64 + n, bf);
  }
  if (t < 256){ a.obl1[t] = ldf(a.bl1, t, bf); a.obg1[t] = ldf(a.bg1, t, bf); }
  if (t < 64){
    a.obl2[t] = (t < 62) ? ldf(a.bl2, t, bf) : 0.f;
    a.obg2[t] = (t < 62) ? ldf(a.bg2, t, bf) : 0.f;
    a.obl3[t] = ldf(a.bl3, t, bf);
    a.obg3[t] = ldf(a.bg3, t, bf);
    a.obg4[t] = ldf(a.bg4, t, bf);
    a.obg5[t] = ldf(a.bg5, t, bf);
    a.obg6[t] = ldf(a.bg6, t, bf);
  }
}

static inline char* wso(void* ws, size_t& off, size_t bytes){
  char* p = (char*)ws + off;
  off += (bytes + 255) & ~(size_t)255;
  return p;
}

extern "C" void kernel_launch(void* const* d_in, const int* in_sizes, int n_in,
                              void* d_out, int out_size, void* d_ws, size_t ws_size,
                              hipStream_t stream){
  // ---- regression guards (validated in R4-R7) ----
  static const int EXP_SIZES[21] = {
    2048*512, 2048*2048, 2048*2048,
    512*256, 256, 256*62, 62, 62*64, 64,
    256*256, 256, 62*62, 62, 64*64, 64,
    64*64, 64, 64*64, 64, 64*64, 64
  };
  float sentinel = 0.f;
  if (n_in != 21) sentinel = 8800000.f;
  if (sentinel == 0.f){
    for (int i = 0; i < 21; ++i)
      if (in_sizes[i] != EXP_SIZES[i]){ sentinel = 100000.f*(float)(i+1); break; }
  }
  if (sentinel == 0.f && out_size != 2048*64) sentinel = 6600000.f;

  // ---- workspace layout ----
  size_t off = 0;
  int*   dflag  = (int*)  wso(d_ws, off, 256);
  int*   ap_cnt = (int*)  wso(d_ws, off, NN*4);
  int*   ap_idx = (int*)  wso(d_ws, off, NN*64*4);
  u64*   colA   = (u64*)  wso(d_ws, off, (size_t)NN*32*8);
  u64*   colB   = (u64*)  wso(d_ws, off, (size_t)NN*32*8);
  u64*   colU   = (u64*)  wso(d_ws, off, (size_t)NN*32*8);
  u64*   rowb   = (u64*)  wso(d_ws, off, (size_t)NN*32*8);
  float* dinv   = (float*)wso(d_ws, off, NN*4);
  int*   mrow   = (int*)  wso(d_ws, off, NN*4);
  float* csum   = (float*)wso(d_ws, off, 256*4);
  float* xf     = (float*)wso(d_ws, off, (size_t)NN*512*4);
  float *tl1 = (float*)wso(d_ws, off, 256*512*4), *tg1 = (float*)wso(d_ws, off, 256*256*4);
  float *tl2 = (float*)wso(d_ws, off,  64*256*4), *tg2 = (float*)wso(d_ws, off,  64*64*4);
  float *tl3 = (float*)wso(d_ws, off,   64*64*4), *tg3 = (float*)wso(d_ws, off,  64*64*4);
  float *tg4 = (float*)wso(d_ws, off,   64*64*4), *tg5 = (float*)wso(d_ws, off,  64*64*4);
  float *tg6 = (float*)wso(d_ws, off,   64*64*4);
  float *obl1 = (float*)wso(d_ws, off, 256*4), *obg1 = (float*)wso(d_ws, off, 256*4);
  float *obl2 = (float*)wso(d_ws, off, 64*4),  *obg2 = (float*)wso(d_ws, off, 64*4);
  float *obl3 = (float*)wso(d_ws, off, 64*4),  *obg3 = (float*)wso(d_ws, off, 64*4);
  float *obg4 = (float*)wso(d_ws, off, 64*4),  *obg5 = (float*)wso(d_ws, off, 64*4);
  float *obg6 = (float*)wso(d_ws, off, 64*4);
  float* hF   = (float*)wso(d_ws, off, (size_t)NN*256*4);
  float* zs   = (float*)wso(d_ws, off, (size_t)NN*256*4);
  float* xF   = (float*)wso(d_ws, off, (size_t)NN*256*4);

  if (sentinel == 0.f && off > ws_size) sentinel = 7700000.f;

  if (sentinel != 0.f){
    sentinel_kernel<<<(NN*64 + 255)/256, 256, 0, stream>>>((float*)d_out, sentinel);
    return;
  }

  const void* x_in = d_in[0];
  const void* An   = d_in[1];
  const void* Ap   = d_in[2];

  probe_kernel<<<1, 256, 0, stream>>>((const u32*)Ap, dflag);
  hipMemsetAsync(ap_cnt, 0, NN*sizeof(int), stream);
  csc_kernel<<<(NN*NN)/256, 256, 0, stream>>>(Ap, ap_cnt, ap_idx, dflag);
  negbits_kernel<<<(NN*32)/256, 256, 0, stream>>>(An, colA, colU, dflag);
  convx_kernel<<<(NN*512)/256, 256, 0, stream>>>(x_in, xf, dflag);

  PrepArgs pa;
  pa.wl1=d_in[3];  pa.bl1=d_in[4];
  pa.wl2=d_in[5];  pa.bl2=d_in[6];
  pa.wl3=d_in[7];  pa.bl3=d_in[8];
  pa.wg1=d_in[9];  pa.bg1=d_in[10];
  pa.wg2=d_in[11]; pa.bg2=d_in[12];
  pa.wg3=d_in[13]; pa.bg3=d_in[14];
  pa.wg4=d_in[15]; pa.bg4=d_in[16];
  pa.wg5=d_in[17]; pa.bg5=d_in[18];
  pa.wg6=d_in[19]; pa.bg6=d_in[20];
  pa.tl1=tl1; pa.tg1=tg1; pa.tl2=tl2; pa.tg2=tg2; pa.tl3=tl3;
  pa.tg3=tg3; pa.tg4=tg4; pa.tg5=tg5; pa.tg6=tg6;
  pa.obl1=obl1; pa.obg1=obg1; pa.obl2=obl2; pa.obg2=obg2; pa.obl3=obl3;
  pa.obg3=obg3; pa.obg4=obg4; pa.obg5=obg5; pa.obg6=obg6;
  pa.flag = dflag;
  prep_kernel<<<512, 256, 0, stream>>>(pa);

  u64 *src = colA, *dst = colB;
  const float wgts[6]  = {1.f, 1.f, 0.5f, 0.5f, 0.25f, 0.25f};
  const int   relus[6] = {1, 1, 1, 1, 1, 0};

  for (int s = 0; s < 6; ++s){
    if (s > 0){
      expand_kernel<<<(NN*32)/256, 256, 0, stream>>>(src, dst, colU, ap_cnt, ap_idx);
      u64* t = src; src = dst; dst = t;
    }
    bittrans_kernel<<<dim3(32,32), 64, 0, stream>>>(colU, rowb);
    degb_kernel<<<NN/256, 256, 0, stream>>>(rowb, dinv, mrow);

    if (s == 0){
      mgemm_kernel<0><<<dim3(32,4), 256, 0, stream>>>(xf, tl1, 256, 512, obl1, nullptr, hF);
      mgemm_kernel<1><<<dim3(32,4), 256, 0, stream>>>(hF, tg1, 256, 256, nullptr, dinv, zs);
      colsumf_kernel<<<4, 256, 0, stream>>>(zs, 256, csum);
      aggb_kernel<256><<<NN, 256, 0, stream>>>(zs, hF, rowb, csum, obg1, dinv, mrow,
                                               wgts[0], relus[0], xF, nullptr);
    } else if (s == 1){
      mgemm_kernel<0><<<dim3(32,1), 256, 0, stream>>>(xF, tl2, 64, 256, obl2, nullptr, hF);
      mgemm_kernel<1><<<dim3(32,1), 256, 0, stream>>>(hF, tg2, 64, 64, nullptr, dinv, zs);
      colsumf_kernel<<<1, 256, 0, stream>>>(zs, 64, csum);
      aggb_kernel<64><<<NN/4, 256, 0, stream>>>(zs, hF, rowb, csum, obg2, dinv, mrow,
                                                wgts[1], relus[1], xF, nullptr);
    } else if (s == 2){
      mgemm_kernel<0><<<dim3(32,1), 256, 0, stream>>>(xF, tl3, 64, 64, obl3, nullptr, hF);
      mgemm_kernel<1><<<dim3(32,1), 256, 0, stream>>>(hF, tg3, 64, 64, nullptr, dinv, zs);
      colsumf_kernel<<<1, 256, 0, stream>>>(zs, 64, csum);
      aggb_kernel<64><<<NN/4, 256, 0, stream>>>(zs, hF, rowb, csum, obg3, dinv, mrow,
                                                wgts[2], relus[2], xF, nullptr);
    } else {
      const float* tg = (s == 3) ? tg4 : (s == 4) ? tg5 : tg6;
      const float* ob = (s == 3) ? obg4 : (s == 4) ? obg5 : obg6;
      mgemm_kernel<1><<<dim3(32,1), 256, 0, stream>>>(xF, tg, 64, 64, nullptr, dinv, zs);
      colsumf_kernel<<<1, 256, 0, stream>>>(zs, 64, csum);
      float* outD = (s == 5) ? (float*)d_out : nullptr;
      aggb_kernel<64><<<NN/4, 256, 0, stream>>>(zs, xF, rowb, csum, ob, dinv, mrow,
                                                wgts[s], relus[s], xF, outD);
    }
  }
}

// Round 10
// 603.833 us; speedup vs baseline: 17.3695x; 2.0487x over previous
//
#include <hip/hip_runtime.h>

typedef unsigned short u16;
typedef unsigned int   u32;
typedef unsigned long long u64;
typedef __attribute__((ext_vector_type(8))) short short8;
typedef __attribute__((ext_vector_type(4))) float f32x4;

#define NN 2048

__device__ __forceinline__ float b2f(u16 u){ union { u32 i; float f; } x; x.i = ((u32)u)<<16; return x.f; }
__device__ __forceinline__ u16 f2b(float f){
  u32 u = __float_as_uint(f);
  u32 r = (u + 0x7fffu + ((u>>16)&1u)) >> 16;
  return (u16)r;
}
// dtype-adaptive load: bf==1 -> bf16 storage, bf==0 -> fp32 storage
__device__ __forceinline__ float ldf(const void* p, size_t i, int bf){
  return bf ? b2f(((const u16*)p)[i]) : ((const float*)p)[i];
}
// split f32 into hi+lo bf16
__device__ __forceinline__ void splitbf(float v, u16& h, u16& l){
  h = f2b(v);
  l = f2b(v - b2f(h));
}

// ---------------- diagnostic sentinel (f32 out) ------------------------------
__global__ __launch_bounds__(256) void sentinel_kernel(float* __restrict__ out, float val){
  int g = blockIdx.x*256 + threadIdx.x;
  if (g < NN*64) out[g] = val;
}

// ---------------- dtype probe: fp32 A_pos words are exactly 0 / 0x3F800000 --
__global__ __launch_bounds__(256) void probe_kernel(const u32* __restrict__ ap, int* __restrict__ flag){
  __shared__ int sb[256];
  int bad = 0;
  for (int i = threadIdx.x; i < 65536; i += 256){
    u32 w = ap[i];
    if (w != 0u && w != 0x3F800000u) bad++;
  }
  sb[threadIdx.x] = bad;
  __syncthreads();
  if (threadIdx.x == 0){
    int t = 0;
    for (int k = 0; k < 256; ++k) t += sb[k];
    *flag = (t > 0) ? 1 : 0;
  }
}

// ---------------- x -> f32 ---------------------------------------------------
__global__ __launch_bounds__(256) void convx_kernel(const void* __restrict__ x, float* __restrict__ xf,
                                                    const int* __restrict__ flag){
  int bf = *flag;
  size_t i = (size_t)blockIdx.x*256 + threadIdx.x;   // 2048*512
  xf[i] = ldf(x, i, bf);
}

// ---------------- CSC of A_pos (per-column nnz lists, cap 64) ----------------
__global__ __launch_bounds__(256) void csc_kernel(const void* __restrict__ Ap,
                                                  int* __restrict__ cnt, int* __restrict__ idx,
                                                  const int* __restrict__ flag){
  int bf = *flag;
  size_t e = (size_t)blockIdx.x*256 + threadIdx.x;   // e = k*2048 + j
  int k = (int)(e >> 11), j = (int)(e & 2047);
  if (ldf(Ap, e, bf) > 0.f){
    int p = atomicAdd(&cnt[j], 1);
    if (p < 64) idx[j*64 + p] = k;
  }
}

// --------------- column bitsets of A_neg: last/union init --------------------
__global__ __launch_bounds__(256) void negbits_kernel(const void* __restrict__ An,
                                                      u64* __restrict__ last, u64* __restrict__ uni,
                                                      const int* __restrict__ flag){
  int bf = *flag;
  int g = blockIdx.x*256 + threadIdx.x;   // 65536 = 2048 cols * 32 words
  int j = g & 2047, w = g >> 11;
  u64 bits = 0;
  for (int b = 0; b < 64; ++b){
    float v = ldf(An, (size_t)(w*64 + b)*NN + j, bf);
    bits |= (u64)(v > 0.f) << b;
  }
  last[(size_t)j*32 + w] = bits;
  uni [(size_t)j*32 + w] = bits;
}

// --------------- expansion: new_col[j] = OR_{k in Ap[:,j]} last_col[k] ------
__global__ __launch_bounds__(256) void expand_kernel(const u64* __restrict__ src, u64* __restrict__ dst,
                                                     u64* __restrict__ uni,
                                                     const int* __restrict__ cnt, const int* __restrict__ idx){
  int g = blockIdx.x*256 + threadIdx.x;   // 65536
  int w = g & 31, j = g >> 5;
  int c = cnt[j]; c = (c > 64) ? 64 : c;
  const int* lst = idx + j*64;
  u64 acc = 0;
  for (int t = 0; t < c; ++t) acc |= src[(size_t)lst[t]*32 + w];
  dst[(size_t)j*32 + w] = acc;
  uni[(size_t)j*32 + w] |= acc;
}

// --------------- 64x64 bit transpose: col bitsets -> row bitsets ------------
__global__ __launch_bounds__(64) void bittrans_kernel(const u64* __restrict__ colb, u64* __restrict__ rowb){
  __shared__ u64 lds[64];
  int wi = blockIdx.x, wj = blockIdx.y;
  int t = threadIdx.x;
  lds[t] = colb[(size_t)(wj*64 + t)*32 + wi];
  __syncthreads();
  u64 out = 0;
#pragma unroll
  for (int tt = 0; tt < 64; ++tt) out |= ((lds[tt] >> t) & 1ULL) << tt;
  rowb[(size_t)(wi*64 + t)*32 + wj] = out;
}

// --------------- row degrees -> dinv ----------------------------------------
__global__ __launch_bounds__(256) void degb_kernel(const u64* __restrict__ rowb,
                                                   float* __restrict__ dinv){
  int i = blockIdx.x*256 + threadIdx.x;   // 2048
  int t = 0;
  for (int w = 0; w < 32; ++w) t += __popcll(rowb[(size_t)i*32 + w]);
  dinv[i] = 1.0f / sqrtf((float)(t + 1));
}

// --------------- split-bf16 MFMA GEMM: C[i][n] = sum_k A[i][k]*Bt[n][k] -----
// MODE 0: + bias[n] ; MODE 1: * dinv[i]
template<int MODE>
__global__ __launch_bounds__(256) void mgemm_kernel(const float* __restrict__ A, const float* __restrict__ Bt,
                                                    int N, int K,
                                                    const float* __restrict__ bias, const float* __restrict__ dinv,
                                                    float* __restrict__ outF){
  constexpr int LDT = 72;
  __shared__ u16 Ah[64*LDT], Al[64*LDT], Bh[64*LDT], Bl[64*LDT];
  const int m0 = blockIdx.x*64, n0 = blockIdx.y*64;
  const int tid = threadIdx.x;
  const int wave = tid >> 6, lane = tid & 63;
  const int wm = (wave>>1)*32, wn = (wave&1)*32;
  const int q = lane >> 4, l16 = lane & 15;
  f32x4 acc00 = {}, acc01 = {}, acc10 = {}, acc11 = {};
  const int sr = tid >> 2, sc = (tid & 3)*16;
  for (int k0 = 0; k0 < K; k0 += 64){
    const float* Ag = A  + (size_t)(m0+sr)*K + k0 + sc;
    const float* Bg = Bt + (size_t)(n0+sr)*K + k0 + sc;
#pragma unroll
    for (int v4 = 0; v4 < 4; ++v4){
      float4 av = ((const float4*)Ag)[v4];
      float4 bv = ((const float4*)Bg)[v4];
      int o = sr*LDT + sc + v4*4;
      splitbf(av.x, Ah[o+0], Al[o+0]); splitbf(av.y, Ah[o+1], Al[o+1]);
      splitbf(av.z, Ah[o+2], Al[o+2]); splitbf(av.w, Ah[o+3], Al[o+3]);
      splitbf(bv.x, Bh[o+0], Bl[o+0]); splitbf(bv.y, Bh[o+1], Bl[o+1]);
      splitbf(bv.z, Bh[o+2], Bl[o+2]); splitbf(bv.w, Bh[o+3], Bl[o+3]);
    }
    __syncthreads();
#pragma unroll
    for (int ks = 0; ks < 2; ++ks){
      const int kb = ks*32 + q*8;
      short8 ah0 = *(const short8*)&Ah[(wm      + l16)*LDT + kb];
      short8 al0 = *(const short8*)&Al[(wm      + l16)*LDT + kb];
      short8 ah1 = *(const short8*)&Ah[(wm + 16 + l16)*LDT + kb];
      short8 al1 = *(const short8*)&Al[(wm + 16 + l16)*LDT + kb];
      short8 bh0 = *(const short8*)&Bh[(wn      + l16)*LDT + kb];
      short8 bl0 = *(const short8*)&Bl[(wn      + l16)*LDT + kb];
      short8 bh1 = *(const short8*)&Bh[(wn + 16 + l16)*LDT + kb];
      short8 bl1 = *(const short8*)&Bl[(wn + 16 + l16)*LDT + kb];
      acc00 = __builtin_amdgcn_mfma_f32_16x16x32_bf16(ah0, bh0, acc00, 0, 0, 0);
      acc00 = __builtin_amdgcn_mfma_f32_16x16x32_bf16(ah0, bl0, acc00, 0, 0, 0);
      acc00 = __builtin_amdgcn_mfma_f32_16x16x32_bf16(al0, bh0, acc00, 0, 0, 0);
      acc01 = __builtin_amdgcn_mfma_f32_16x16x32_bf16(ah0, bh1, acc01, 0, 0, 0);
      acc01 = __builtin_amdgcn_mfma_f32_16x16x32_bf16(ah0, bl1, acc01, 0, 0, 0);
      acc01 = __builtin_amdgcn_mfma_f32_16x16x32_bf16(al0, bh1, acc01, 0, 0, 0);
      acc10 = __builtin_amdgcn_mfma_f32_16x16x32_bf16(ah1, bh0, acc10, 0, 0, 0);
      acc10 = __builtin_amdgcn_mfma_f32_16x16x32_bf16(ah1, bl0, acc10, 0, 0, 0);
      acc10 = __builtin_amdgcn_mfma_f32_16x16x32_bf16(al1, bh0, acc10, 0, 0, 0);
      acc11 = __builtin_amdgcn_mfma_f32_16x16x32_bf16(ah1, bh1, acc11, 0, 0, 0);
      acc11 = __builtin_amdgcn_mfma_f32_16x16x32_bf16(ah1, bl1, acc11, 0, 0, 0);
      acc11 = __builtin_amdgcn_mfma_f32_16x16x32_bf16(al1, bh1, acc11, 0, 0, 0);
    }
    __syncthreads();
  }
#pragma unroll
  for (int mi = 0; mi < 2; ++mi)
#pragma unroll
  for (int ni = 0; ni < 2; ++ni){
    f32x4 a = (mi == 0) ? ((ni == 0) ? acc00 : acc01) : ((ni == 0) ? acc10 : acc11);
#pragma unroll
    for (int r = 0; r < 4; ++r){
      int i = m0 + wm + mi*16 + q*4 + r;
      int n = n0 + wn + ni*16 + l16;
      float v = a[r];
      if constexpr (MODE == 0) v += bias[n];
      else                     v *= dinv[i];
      outF[(size_t)i*N + n] = v;
    }
  }
}

// --------------- bitmask-MFMA aggregation + GCN epilogue --------------------
// y = U @ zs. A from row bitsets (exact 0/1), B = zs split hi/lo (2 passes).
// zs is K x F row-major -> stage TRANSPOSED into LDS so rows are n (fragment
// reads expect B[row=n][col=k], matching mgemm's verified convention).
template<int F>
__global__ __launch_bounds__(256) void magg_kernel(const float* __restrict__ zs, const float* __restrict__ h,
                                                   const u64* __restrict__ rowb,
                                                   const float* __restrict__ bias, const float* __restrict__ dinv,
                                                   float wgt, int doRelu,
                                                   float* __restrict__ outF, float* __restrict__ outD){
  constexpr int LDT = 72;
  constexpr int LBS = 33;
  __shared__ u16 Bh[64*LDT], Bl[64*LDT];
  __shared__ u64 RB[64*LBS];
  const int m0 = blockIdx.x*64, n0 = blockIdx.y*64;
  const int tid = threadIdx.x;
  const int wave = tid >> 6, lane = tid & 63;
  const int wm = (wave>>1)*32, wn = (wave&1)*32;
  const int q = lane >> 4, l16 = lane & 15;
  // preload this block's 64 rows of bitsets (16 KB)
  for (int t = tid; t < 64*32; t += 256){
    int lr = t >> 5, w = t & 31;
    RB[lr*LBS + w] = rowb[(size_t)(m0 + lr)*32 + w];
  }
  f32x4 acc00 = {}, acc01 = {}, acc10 = {}, acc11 = {};
  const int sr = tid >> 2, sc = (tid & 3)*16;
  for (int k0 = 0; k0 < NN; k0 += 64){
    const float* Bg = zs + (size_t)(k0+sr)*F + n0 + sc;   // coalesced float4 reads
#pragma unroll
    for (int v4 = 0; v4 < 4; ++v4){
      float4 bv = ((const float4*)Bg)[v4];
      int nl = sc + v4*4;
      u16 hh, ll;
      // transposed scalar writes: LDS row = n_local, col = k_local (=sr)
      splitbf(bv.x, hh, ll); Bh[(nl+0)*LDT + sr] = hh; Bl[(nl+0)*LDT + sr] = ll;
      splitbf(bv.y, hh, ll); Bh[(nl+1)*LDT + sr] = hh; Bl[(nl+1)*LDT + sr] = ll;
      splitbf(bv.z, hh, ll); Bh[(nl+2)*LDT + sr] = hh; Bl[(nl+2)*LDT + sr] = ll;
      splitbf(bv.w, hh, ll); Bh[(nl+3)*LDT + sr] = hh; Bl[(nl+3)*LDT + sr] = ll;
    }
    __syncthreads();
    const int wd = k0 >> 6;                // wave-uniform word index
#pragma unroll
    for (int ks = 0; ks < 2; ++ks){
      const int kk = ks*32 + q*8;
      u64 w0 = RB[(wm      + l16)*LBS + wd];
      u64 w1 = RB[(wm + 16 + l16)*LBS + wd];
      u32 by0 = (u32)(w0 >> kk) & 0xFFu;
      u32 by1 = (u32)(w1 >> kk) & 0xFFu;
      short8 a0, a1;
#pragma unroll
      for (int j = 0; j < 8; ++j){
        a0[j] = (short)(((by0 >> j) & 1u) ? 0x3F80 : 0);
        a1[j] = (short)(((by1 >> j) & 1u) ? 0x3F80 : 0);
      }
      short8 bh0 = *(const short8*)&Bh[(wn      + l16)*LDT + kk];
      short8 bl0 = *(const short8*)&Bl[(wn      + l16)*LDT + kk];
      short8 bh1 = *(const short8*)&Bh[(wn + 16 + l16)*LDT + kk];
      short8 bl1 = *(const short8*)&Bl[(wn + 16 + l16)*LDT + kk];
      acc00 = __builtin_amdgcn_mfma_f32_16x16x32_bf16(a0, bh0, acc00, 0, 0, 0);
      acc00 = __builtin_amdgcn_mfma_f32_16x16x32_bf16(a0, bl0, acc00, 0, 0, 0);
      acc01 = __builtin_amdgcn_mfma_f32_16x16x32_bf16(a0, bh1, acc01, 0, 0, 0);
      acc01 = __builtin_amdgcn_mfma_f32_16x16x32_bf16(a0, bl1, acc01, 0, 0, 0);
      acc10 = __builtin_amdgcn_mfma_f32_16x16x32_bf16(a1, bh0, acc10, 0, 0, 0);
      acc10 = __builtin_amdgcn_mfma_f32_16x16x32_bf16(a1, bl0, acc10, 0, 0, 0);
      acc11 = __builtin_amdgcn_mfma_f32_16x16x32_bf16(a1, bh1, acc11, 0, 0, 0);
      acc11 = __builtin_amdgcn_mfma_f32_16x16x32_bf16(a1, bl1, acc11, 0, 0, 0);
    }
    __syncthreads();
  }
#pragma unroll
  for (int mi = 0; mi < 2; ++mi)
#pragma unroll
  for (int ni = 0; ni < 2; ++ni){
    f32x4 a = (mi == 0) ? ((ni == 0) ? acc00 : acc01) : ((ni == 0) ? acc10 : acc11);
#pragma unroll
    for (int r = 0; r < 4; ++r){
      int i = m0 + wm + mi*16 + q*4 + r;
      int n = n0 + wn + ni*16 + l16;
      float o = dinv[i]*(a[r] + zs[(size_t)i*F + n]) + bias[n];
      if (doRelu) o = fmaxf(o, 0.f);
      float xn = h[(size_t)i*F + n] + wgt*o;
      outF[(size_t)i*F + n] = xn;
      if (outD) outD[(size_t)i*F + n] = xn;
    }
  }
}

// --------------- weight transpose + padding, all f32 ------------------------
struct PrepArgs {
  const void *wl1,*bl1,*wl2,*bl2,*wl3,*bl3,*wg1,*bg1,*wg2,*bg2,*wg3,*bg3,*wg4,*bg4,*wg5,*bg5,*wg6,*bg6;
  float *tl1,*tg1,*tl2,*tg2,*tl3,*tg3,*tg4,*tg5,*tg6;
  float *obl1,*obg1,*obl2,*obg2,*obl3,*obg3,*obg4,*obg5,*obg6;
  const int* flag;
};

__global__ __launch_bounds__(256) void prep_kernel(PrepArgs a){
  int bf = *a.flag;
  int t = blockIdx.x*256 + threadIdx.x;     // 131072 threads
  if (t < 256*512){ int n = t>>9, k = t&511; a.tl1[t] = ldf(a.wl1, (size_t)k*256 + n, bf); }
  if (t < 256*256){ int n = t>>8, k = t&255; a.tg1[t] = ldf(a.wg1, (size_t)k*256 + n, bf); }
  if (t <  64*256){ int n = t>>8, k = t&255; a.tl2[t] = (n < 62) ? ldf(a.wl2, (size_t)k*62 + n, bf) : 0.f; }
  if (t <  64*64){
    int n = t>>6, k = t&63;
    a.tg2[t] = (n < 62 && k < 62) ? ldf(a.wg2, (size_t)k*62 + n, bf) : 0.f;
    a.tl3[t] = (k < 62) ? ldf(a.wl3, (size_t)k*64 + n, bf) : 0.f;
    a.tg3[t] = ldf(a.wg3, (size_t)k*64 + n, bf);
    a.tg4[t] = ldf(a.wg4, (size_t)k*64 + n, bf);
    a.tg5[t] = ldf(a.wg5, (size_t)k*64 + n, bf);
    a.tg6[t] = ldf(a.wg6, (size_t)k*64 + n, bf);
  }
  if (t < 256){ a.obl1[t] = ldf(a.bl1, t, bf); a.obg1[t] = ldf(a.bg1, t, bf); }
  if (t < 64){
    a.obl2[t] = (t < 62) ? ldf(a.bl2, t, bf) : 0.f;
    a.obg2[t] = (t < 62) ? ldf(a.bg2, t, bf) : 0.f;
    a.obl3[t] = ldf(a.bl3, t, bf);
    a.obg3[t] = ldf(a.bg3, t, bf);
    a.obg4[t] = ldf(a.bg4, t, bf);
    a.obg5[t] = ldf(a.bg5, t, bf);
    a.obg6[t] = ldf(a.bg6, t, bf);
  }
}

static inline char* wso(void* ws, size_t& off, size_t bytes){
  char* p = (char*)ws + off;
  off += (bytes + 255) & ~(size_t)255;
  return p;
}

extern "C" void kernel_launch(void* const* d_in, const int* in_sizes, int n_in,
                              void* d_out, int out_size, void* d_ws, size_t ws_size,
                              hipStream_t stream){
  // ---- regression guards ----
  static const int EXP_SIZES[21] = {
    2048*512, 2048*2048, 2048*2048,
    512*256, 256, 256*62, 62, 62*64, 64,
    256*256, 256, 62*62, 62, 64*64, 64,
    64*64, 64, 64*64, 64, 64*64, 64
  };
  float sentinel = 0.f;
  if (n_in != 21) sentinel = 8800000.f;
  if (sentinel == 0.f){
    for (int i = 0; i < 21; ++i)
      if (in_sizes[i] != EXP_SIZES[i]){ sentinel = 100000.f*(float)(i+1); break; }
  }
  if (sentinel == 0.f && out_size != 2048*64) sentinel = 6600000.f;

  // ---- workspace layout ----
  size_t off = 0;
  int*   dflag  = (int*)  wso(d_ws, off, 256);
  int*   ap_cnt = (int*)  wso(d_ws, off, NN*4);
  int*   ap_idx = (int*)  wso(d_ws, off, NN*64*4);
  u64*   colA   = (u64*)  wso(d_ws, off, (size_t)NN*32*8);
  u64*   colB   = (u64*)  wso(d_ws, off, (size_t)NN*32*8);
  u64*   colU   = (u64*)  wso(d_ws, off, (size_t)NN*32*8);
  u64*   rowb   = (u64*)  wso(d_ws, off, (size_t)NN*32*8);
  float* dinv   = (float*)wso(d_ws, off, NN*4);
  float* xf     = (float*)wso(d_ws, off, (size_t)NN*512*4);
  float *tl1 = (float*)wso(d_ws, off, 256*512*4), *tg1 = (float*)wso(d_ws, off, 256*256*4);
  float *tl2 = (float*)wso(d_ws, off,  64*256*4), *tg2 = (float*)wso(d_ws, off,  64*64*4);
  float *tl3 = (float*)wso(d_ws, off,   64*64*4), *tg3 = (float*)wso(d_ws, off,  64*64*4);
  float *tg4 = (float*)wso(d_ws, off,   64*64*4), *tg5 = (float*)wso(d_ws, off,  64*64*4);
  float *tg6 = (float*)wso(d_ws, off,   64*64*4);
  float *obl1 = (float*)wso(d_ws, off, 256*4), *obg1 = (float*)wso(d_ws, off, 256*4);
  float *obl2 = (float*)wso(d_ws, off, 64*4),  *obg2 = (float*)wso(d_ws, off, 64*4);
  float *obl3 = (float*)wso(d_ws, off, 64*4),  *obg3 = (float*)wso(d_ws, off, 64*4);
  float *obg4 = (float*)wso(d_ws, off, 64*4),  *obg5 = (float*)wso(d_ws, off, 64*4);
  float *obg6 = (float*)wso(d_ws, off, 64*4);
  float* hF   = (float*)wso(d_ws, off, (size_t)NN*256*4);
  float* zs   = (float*)wso(d_ws, off, (size_t)NN*256*4);
  float* xF   = (float*)wso(d_ws, off, (size_t)NN*256*4);

  if (sentinel == 0.f && off > ws_size) sentinel = 7700000.f;

  if (sentinel != 0.f){
    sentinel_kernel<<<(NN*64 + 255)/256, 256, 0, stream>>>((float*)d_out, sentinel);
    return;
  }

  const void* x_in = d_in[0];
  const void* An   = d_in[1];
  const void* Ap   = d_in[2];

  probe_kernel<<<1, 256, 0, stream>>>((const u32*)Ap, dflag);
  hipMemsetAsync(ap_cnt, 0, NN*sizeof(int), stream);
  csc_kernel<<<(NN*NN)/256, 256, 0, stream>>>(Ap, ap_cnt, ap_idx, dflag);
  negbits_kernel<<<(NN*32)/256, 256, 0, stream>>>(An, colA, colU, dflag);
  convx_kernel<<<(NN*512)/256, 256, 0, stream>>>(x_in, xf, dflag);

  PrepArgs pa;
  pa.wl1=d_in[3];  pa.bl1=d_in[4];
  pa.wl2=d_in[5];  pa.bl2=d_in[6];
  pa.wl3=d_in[7];  pa.bl3=d_in[8];
  pa.wg1=d_in[9];  pa.bg1=d_in[10];
  pa.wg2=d_in[11]; pa.bg2=d_in[12];
  pa.wg3=d_in[13]; pa.bg3=d_in[14];
  pa.wg4=d_in[15]; pa.bg4=d_in[16];
  pa.wg5=d_in[17]; pa.bg5=d_in[18];
  pa.wg6=d_in[19]; pa.bg6=d_in[20];
  pa.tl1=tl1; pa.tg1=tg1; pa.tl2=tl2; pa.tg2=tg2; pa.tl3=tl3;
  pa.tg3=tg3; pa.tg4=tg4; pa.tg5=tg5; pa.tg6=tg6;
  pa.obl1=obl1; pa.obg1=obg1; pa.obl2=obl2; pa.obg2=obg2; pa.obl3=obl3;
  pa.obg3=obg3; pa.obg4=obg4; pa.obg5=obg5; pa.obg6=obg6;
  pa.flag = dflag;
  prep_kernel<<<512, 256, 0, stream>>>(pa);

  u64 *src = colA, *dst = colB;
  const float wgts[6]  = {1.f, 1.f, 0.5f, 0.5f, 0.25f, 0.25f};
  const int   relus[6] = {1, 1, 1, 1, 1, 0};

  for (int s = 0; s < 6; ++s){
    if (s > 0){
      expand_kernel<<<(NN*32)/256, 256, 0, stream>>>(src, dst, colU, ap_cnt, ap_idx);
      u64* t = src; src = dst; dst = t;
    }
    bittrans_kernel<<<dim3(32,32), 64, 0, stream>>>(colU, rowb);
    degb_kernel<<<NN/256, 256, 0, stream>>>(rowb, dinv);

    if (s == 0){
      mgemm_kernel<0><<<dim3(32,4), 256, 0, stream>>>(xf, tl1, 256, 512, obl1, nullptr, hF);
      mgemm_kernel<1><<<dim3(32,4), 256, 0, stream>>>(hF, tg1, 256, 256, nullptr, dinv, zs);
      magg_kernel<256><<<dim3(32,4), 256, 0, stream>>>(zs, hF, rowb, obg1, dinv,
                                                       wgts[0], relus[0], xF, nullptr);
    } else if (s == 1){
      mgemm_kernel<0><<<dim3(32,1), 256, 0, stream>>>(xF, tl2, 64, 256, obl2, nullptr, hF);
      mgemm_kernel<1><<<dim3(32,1), 256, 0, stream>>>(hF, tg2, 64, 64, nullptr, dinv, zs);
      magg_kernel<64><<<dim3(32,1), 256, 0, stream>>>(zs, hF, rowb, obg2, dinv,
                                                      wgts[1], relus[1], xF, nullptr);
    } else if (s == 2){
      mgemm_kernel<0><<<dim3(32,1), 256, 0, stream>>>(xF, tl3, 64, 64, obl3, nullptr, hF);
      mgemm_kernel<1><<<dim3(32,1), 256, 0, stream>>>(hF, tg3, 64, 64, nullptr, dinv, zs);
      magg_kernel<64><<<dim3(32,1), 256, 0, stream>>>(zs, hF, rowb, obg3, dinv,
                                                      wgts[2], relus[2], xF, nullptr);
    } else {
      const float* tg = (s == 3) ? tg4 : (s == 4) ? tg5 : tg6;
      const float* ob = (s == 3) ? obg4 : (s == 4) ? obg5 : obg6;
      mgemm_kernel<1><<<dim3(32,1), 256, 0, stream>>>(xF, tg, 64, 64, nullptr, dinv, zs);
      float* outD = (s == 5) ? (float*)d_out : nullptr;
      magg_kernel<64><<<dim3(32,1), 256, 0, stream>>>(zs, xF, rowb, ob, dinv,
                                                      wgts[s], relus[s], xF, outD);
    }
  }
}

// Round 11
// 393.552 us; speedup vs baseline: 26.6503x; 1.5343x over previous
//
#include <hip/hip_runtime.h>

typedef unsigned short u16;
typedef unsigned int   u32;
typedef unsigned long long u64;
typedef __attribute__((ext_vector_type(8))) short short8;
typedef __attribute__((ext_vector_type(4))) float f32x4;

#define NN 2048

__device__ __forceinline__ float b2f(u16 u){ union { u32 i; float f; } x; x.i = ((u32)u)<<16; return x.f; }
__device__ __forceinline__ u16 f2b(float f){
  u32 u = __float_as_uint(f);
  u32 r = (u + 0x7fffu + ((u>>16)&1u)) >> 16;
  return (u16)r;
}
__device__ __forceinline__ float ldf(const void* p, size_t i, int bf){
  return bf ? b2f(((const u16*)p)[i]) : ((const float*)p)[i];
}
__device__ __forceinline__ void splitbf(float v, u16& h, u16& l){
  h = f2b(v);
  l = f2b(v - b2f(h));
}

// ---------------- diagnostic sentinel (f32 out) ------------------------------
__global__ __launch_bounds__(256) void sentinel_kernel(float* __restrict__ out, float val){
  int g = blockIdx.x*256 + threadIdx.x;
  if (g < NN*64) out[g] = val;
}

// ---------------- dtype probe (parallel): fp32 words are 0 / 0x3F800000 -----
__global__ __launch_bounds__(256) void probe_kernel(const u32* __restrict__ ap, int* __restrict__ flag){
  int i = blockIdx.x*256 + threadIdx.x;   // 65536 words
  u32 w = ap[i];
  if (w != 0u && w != 0x3F800000u) atomicOr(flag, 1);
}

// ---------------- x -> f32 ---------------------------------------------------
__global__ __launch_bounds__(256) void convx_kernel(const void* __restrict__ x, float* __restrict__ xf,
                                                    const int* __restrict__ flag){
  int bf = *flag;
  size_t i = (size_t)blockIdx.x*256 + threadIdx.x;   // 2048*512
  xf[i] = ldf(x, i, bf);
}

// ---------------- CSC of A_pos (per-column nnz lists, cap 64) ----------------
__global__ __launch_bounds__(256) void csc_kernel(const void* __restrict__ Ap,
                                                  int* __restrict__ cnt, int* __restrict__ idx,
                                                  const int* __restrict__ flag){
  int bf = *flag;
  size_t e = (size_t)blockIdx.x*256 + threadIdx.x;   // e = k*2048 + j
  int k = (int)(e >> 11), j = (int)(e & 2047);
  if (ldf(Ap, e, bf) > 0.f){
    int p = atomicAdd(&cnt[j], 1);
    if (p < 64) idx[j*64 + p] = k;
  }
}

// --------------- column bitsets of A_neg: last/union init --------------------
__global__ __launch_bounds__(256) void negbits_kernel(const void* __restrict__ An,
                                                      u64* __restrict__ last, u64* __restrict__ uni,
                                                      const int* __restrict__ flag){
  int bf = *flag;
  int g = blockIdx.x*256 + threadIdx.x;   // 65536 = 2048 cols * 32 words
  int j = g & 2047, w = g >> 11;
  u64 bits = 0;
  for (int b = 0; b < 64; ++b){
    float v = ldf(An, (size_t)(w*64 + b)*NN + j, bf);
    bits |= (u64)(v > 0.f) << b;
  }
  last[(size_t)j*32 + w] = bits;
  uni [(size_t)j*32 + w] = bits;
}

// --------------- expansion: new_col[j] = OR_{k in Ap[:,j]} last_col[k] ------
__global__ __launch_bounds__(256) void expand_kernel(const u64* __restrict__ src, u64* __restrict__ dst,
                                                     u64* __restrict__ uni,
                                                     const int* __restrict__ cnt, const int* __restrict__ idx){
  int g = blockIdx.x*256 + threadIdx.x;   // 65536
  int w = g & 31, j = g >> 5;
  int c = cnt[j]; c = (c > 64) ? 64 : c;
  const int* lst = idx + j*64;
  u64 acc = 0;
  for (int t = 0; t < c; ++t) acc |= src[(size_t)lst[t]*32 + w];
  dst[(size_t)j*32 + w] = acc;
  uni[(size_t)j*32 + w] |= acc;
}

// --------------- 64x64 bit transpose: col bitsets -> row bitsets ------------
__global__ __launch_bounds__(64) void bittrans_kernel(const u64* __restrict__ colb, u64* __restrict__ rowb){
  __shared__ u64 lds[64];
  int wi = blockIdx.x, wj = blockIdx.y;
  int t = threadIdx.x;
  lds[t] = colb[(size_t)(wj*64 + t)*32 + wi];
  __syncthreads();
  u64 out = 0;
#pragma unroll
  for (int tt = 0; tt < 64; ++tt) out |= ((lds[tt] >> t) & 1ULL) << tt;
  rowb[(size_t)(wi*64 + t)*32 + wj] = out;
}

// --------------- row degrees -> dinv ----------------------------------------
__global__ __launch_bounds__(256) void degb_kernel(const u64* __restrict__ rowb,
                                                   float* __restrict__ dinv){
  int i = blockIdx.x*256 + threadIdx.x;   // 2048
  int t = 0;
  for (int w = 0; w < 32; ++w) t += __popcll(rowb[(size_t)i*32 + w]);
  dinv[i] = 1.0f / sqrtf((float)(t + 1));
}

// --------------- split-bf16 MFMA GEMM: C[i][n] = sum_k A[i][k]*Bt[n][k] -----
// MODE 0: + bias[n] ; MODE 1: * dinv[i]
template<int MODE>
__global__ __launch_bounds__(256) void mgemm_kernel(const float* __restrict__ A, const float* __restrict__ Bt,
                                                    int N, int K,
                                                    const float* __restrict__ bias, const float* __restrict__ dinv,
                                                    float* __restrict__ outF){
  constexpr int LDT = 72;
  __shared__ u16 Ah[64*LDT], Al[64*LDT], Bh[64*LDT], Bl[64*LDT];
  const int m0 = blockIdx.x*64, n0 = blockIdx.y*64;
  const int tid = threadIdx.x;
  const int wave = tid >> 6, lane = tid & 63;
  const int wm = (wave>>1)*32, wn = (wave&1)*32;
  const int q = lane >> 4, l16 = lane & 15;
  f32x4 acc00 = {}, acc01 = {}, acc10 = {}, acc11 = {};
  const int sr = tid >> 2, sc = (tid & 3)*16;
  for (int k0 = 0; k0 < K; k0 += 64){
    const float* Ag = A  + (size_t)(m0+sr)*K + k0 + sc;
    const float* Bg = Bt + (size_t)(n0+sr)*K + k0 + sc;
#pragma unroll
    for (int v4 = 0; v4 < 4; ++v4){
      float4 av = ((const float4*)Ag)[v4];
      float4 bv = ((const float4*)Bg)[v4];
      int o = sr*LDT + sc + v4*4;
      splitbf(av.x, Ah[o+0], Al[o+0]); splitbf(av.y, Ah[o+1], Al[o+1]);
      splitbf(av.z, Ah[o+2], Al[o+2]); splitbf(av.w, Ah[o+3], Al[o+3]);
      splitbf(bv.x, Bh[o+0], Bl[o+0]); splitbf(bv.y, Bh[o+1], Bl[o+1]);
      splitbf(bv.z, Bh[o+2], Bl[o+2]); splitbf(bv.w, Bh[o+3], Bl[o+3]);
    }
    __syncthreads();
#pragma unroll
    for (int ks = 0; ks < 2; ++ks){
      const int kb = ks*32 + q*8;
      short8 ah0 = *(const short8*)&Ah[(wm      + l16)*LDT + kb];
      short8 al0 = *(const short8*)&Al[(wm      + l16)*LDT + kb];
      short8 ah1 = *(const short8*)&Ah[(wm + 16 + l16)*LDT + kb];
      short8 al1 = *(const short8*)&Al[(wm + 16 + l16)*LDT + kb];
      short8 bh0 = *(const short8*)&Bh[(wn      + l16)*LDT + kb];
      short8 bl0 = *(const short8*)&Bl[(wn      + l16)*LDT + kb];
      short8 bh1 = *(const short8*)&Bh[(wn + 16 + l16)*LDT + kb];
      short8 bl1 = *(const short8*)&Bl[(wn + 16 + l16)*LDT + kb];
      acc00 = __builtin_amdgcn_mfma_f32_16x16x32_bf16(ah0, bh0, acc00, 0, 0, 0);
      acc00 = __builtin_amdgcn_mfma_f32_16x16x32_bf16(ah0, bl0, acc00, 0, 0, 0);
      acc00 = __builtin_amdgcn_mfma_f32_16x16x32_bf16(al0, bh0, acc00, 0, 0, 0);
      acc01 = __builtin_amdgcn_mfma_f32_16x16x32_bf16(ah0, bh1, acc01, 0, 0, 0);
      acc01 = __builtin_amdgcn_mfma_f32_16x16x32_bf16(ah0, bl1, acc01, 0, 0, 0);
      acc01 = __builtin_amdgcn_mfma_f32_16x16x32_bf16(al0, bh1, acc01, 0, 0, 0);
      acc10 = __builtin_amdgcn_mfma_f32_16x16x32_bf16(ah1, bh0, acc10, 0, 0, 0);
      acc10 = __builtin_amdgcn_mfma_f32_16x16x32_bf16(ah1, bl0, acc10, 0, 0, 0);
      acc10 = __builtin_amdgcn_mfma_f32_16x16x32_bf16(al1, bh0, acc10, 0, 0, 0);
      acc11 = __builtin_amdgcn_mfma_f32_16x16x32_bf16(ah1, bh1, acc11, 0, 0, 0);
      acc11 = __builtin_amdgcn_mfma_f32_16x16x32_bf16(ah1, bl1, acc11, 0, 0, 0);
      acc11 = __builtin_amdgcn_mfma_f32_16x16x32_bf16(al1, bh1, acc11, 0, 0, 0);
    }
    __syncthreads();
  }
#pragma unroll
  for (int mi = 0; mi < 2; ++mi)
#pragma unroll
  for (int ni = 0; ni < 2; ++ni){
    f32x4 a = (mi == 0) ? ((ni == 0) ? acc00 : acc01) : ((ni == 0) ? acc10 : acc11);
#pragma unroll
    for (int r = 0; r < 4; ++r){
      int i = m0 + wm + mi*16 + q*4 + r;
      int n = n0 + wn + ni*16 + l16;
      float v = a[r];
      if constexpr (MODE == 0) v += bias[n];
      else                     v *= dinv[i];
      outF[(size_t)i*N + n] = v;
    }
  }
}

// --------------- split-K bitmask-MFMA aggregation (partials) ----------------
// y = U @ zs. A-fragments expanded from row bitsets (exact); B loaded DIRECTLY
// from global (4x64B segments per instr, L1/L2-resident), split hi/lo in-reg.
// No LDS, no barriers. grid = (32, F/64, KS); each z computes a K-chunk.
template<int F>
__global__ __launch_bounds__(256) void maggp_kernel(const float* __restrict__ zs,
                                                    const u64* __restrict__ rowb,
                                                    float* __restrict__ part, int KCH){
  const int m0 = blockIdx.x*64, n0 = blockIdx.y*64, kc0 = blockIdx.z*KCH;
  const int tid = threadIdx.x;
  const int wave = tid >> 6, lane = tid & 63;
  const int wm = (wave>>1)*32, wn = (wave&1)*32;
  const int q = lane >> 4, l16 = lane & 15;
  f32x4 acc00 = {}, acc01 = {}, acc10 = {}, acc11 = {};
  for (int k0 = kc0; k0 < kc0 + KCH; k0 += 64){
    const int wd = k0 >> 6;
    u64 w0 = rowb[(size_t)(m0 + wm      + l16)*32 + wd];
    u64 w1 = rowb[(size_t)(m0 + wm + 16 + l16)*32 + wd];
#pragma unroll
    for (int ks = 0; ks < 2; ++ks){
      const int kk = ks*32 + q*8;
      u32 by0 = (u32)(w0 >> kk) & 0xFFu;
      u32 by1 = (u32)(w1 >> kk) & 0xFFu;
      short8 a0, a1;
#pragma unroll
      for (int j = 0; j < 8; ++j){
        a0[j] = (short)(((by0 >> j) & 1u) ? 0x3F80 : 0);
        a1[j] = (short)(((by1 >> j) & 1u) ? 0x3F80 : 0);
      }
      const float* B0 = zs + (size_t)(k0 + kk)*F + n0;
      short8 bh0, bl0, bh1, bl1;
#pragma unroll
      for (int j = 0; j < 8; ++j){
        u16 hh, ll;
        splitbf(B0[(size_t)j*F + wn      + l16], hh, ll); bh0[j] = (short)hh; bl0[j] = (short)ll;
        splitbf(B0[(size_t)j*F + wn + 16 + l16], hh, ll); bh1[j] = (short)hh; bl1[j] = (short)ll;
      }
      acc00 = __builtin_amdgcn_mfma_f32_16x16x32_bf16(a0, bh0, acc00, 0, 0, 0);
      acc00 = __builtin_amdgcn_mfma_f32_16x16x32_bf16(a0, bl0, acc00, 0, 0, 0);
      acc01 = __builtin_amdgcn_mfma_f32_16x16x32_bf16(a0, bh1, acc01, 0, 0, 0);
      acc01 = __builtin_amdgcn_mfma_f32_16x16x32_bf16(a0, bl1, acc01, 0, 0, 0);
      acc10 = __builtin_amdgcn_mfma_f32_16x16x32_bf16(a1, bh0, acc10, 0, 0, 0);
      acc10 = __builtin_amdgcn_mfma_f32_16x16x32_bf16(a1, bl0, acc10, 0, 0, 0);
      acc11 = __builtin_amdgcn_mfma_f32_16x16x32_bf16(a1, bh1, acc11, 0, 0, 0);
      acc11 = __builtin_amdgcn_mfma_f32_16x16x32_bf16(a1, bl1, acc11, 0, 0, 0);
    }
  }
  float* p = part + (size_t)blockIdx.z*NN*F;
#pragma unroll
  for (int mi = 0; mi < 2; ++mi)
#pragma unroll
  for (int ni = 0; ni < 2; ++ni){
    f32x4 a = (mi == 0) ? ((ni == 0) ? acc00 : acc01) : ((ni == 0) ? acc10 : acc11);
#pragma unroll
    for (int r = 0; r < 4; ++r){
      int i = m0 + wm + mi*16 + q*4 + r;
      int n = n0 + wn + ni*16 + l16;
      p[(size_t)i*F + n] = a[r];
    }
  }
}

// --------------- split-K reduce + GCN epilogue ------------------------------
template<int F>
__global__ __launch_bounds__(256) void magge_kernel(const float* __restrict__ part,
                                                    const float* __restrict__ zs, const float* __restrict__ h,
                                                    const float* __restrict__ bias, const float* __restrict__ dinv,
                                                    int KS, float wgt, int doRelu,
                                                    float* __restrict__ outF, float* __restrict__ outD){
  int g = blockIdx.x*256 + threadIdx.x;   // 2048*F
  int n = g & (F - 1);
  int i = g / F;
  float y = 0.f;
  for (int s = 0; s < KS; ++s) y += part[(size_t)s*NN*F + g];
  float o = dinv[i]*(y + zs[g]) + bias[n];
  if (doRelu) o = fmaxf(o, 0.f);
  float xn = h[g] + wgt*o;
  outF[g] = xn;
  if (outD) outD[g] = xn;
}

// --------------- weight transpose + padding, all f32 ------------------------
struct PrepArgs {
  const void *wl1,*bl1,*wl2,*bl2,*wl3,*bl3,*wg1,*bg1,*wg2,*bg2,*wg3,*bg3,*wg4,*bg4,*wg5,*bg5,*wg6,*bg6;
  float *tl1,*tg1,*tl2,*tg2,*tl3,*tg3,*tg4,*tg5,*tg6;
  float *obl1,*obg1,*obl2,*obg2,*obl3,*obg3,*obg4,*obg5,*obg6;
  const int* flag;
};

__global__ __launch_bounds__(256) void prep_kernel(PrepArgs a){
  int bf = *a.flag;
  int t = blockIdx.x*256 + threadIdx.x;     // 131072 threads
  if (t < 256*512){ int n = t>>9, k = t&511; a.tl1[t] = ldf(a.wl1, (size_t)k*256 + n, bf); }
  if (t < 256*256){ int n = t>>8, k = t&255; a.tg1[t] = ldf(a.wg1, (size_t)k*256 + n, bf); }
  if (t <  64*256){ int n = t>>8, k = t&255; a.tl2[t] = (n < 62) ? ldf(a.wl2, (size_t)k*62 + n, bf) : 0.f; }
  if (t <  64*64){
    int n = t>>6, k = t&63;
    a.tg2[t] = (n < 62 && k < 62) ? ldf(a.wg2, (size_t)k*62 + n, bf) : 0.f;
    a.tl3[t] = (k < 62) ? ldf(a.wl3, (size_t)k*64 + n, bf) : 0.f;
    a.tg3[t] = ldf(a.wg3, (size_t)k*64 + n, bf);
    a.tg4[t] = ldf(a.wg4, (size_t)k*64 + n, bf);
    a.tg5[t] = ldf(a.wg5, (size_t)k*64 + n, bf);
    a.tg6[t] = ldf(a.wg6, (size_t)k*64 + n, bf);
  }
  if (t < 256){ a.obl1[t] = ldf(a.bl1, t, bf); a.obg1[t] = ldf(a.bg1, t, bf); }
  if (t < 64){
    a.obl2[t] = (t < 62) ? ldf(a.bl2, t, bf) : 0.f;
    a.obg2[t] = (t < 62) ? ldf(a.bg2, t, bf) : 0.f;
    a.obl3[t] = ldf(a.bl3, t, bf);
    a.obg3[t] = ldf(a.bg3, t, bf);
    a.obg4[t] = ldf(a.bg4, t, bf);
    a.obg5[t] = ldf(a.bg5, t, bf);
    a.obg6[t] = ldf(a.bg6, t, bf);
  }
}

static inline char* wso(void* ws, size_t& off, size_t bytes){
  char* p = (char*)ws + off;
  off += (bytes + 255) & ~(size_t)255;
  return p;
}

extern "C" void kernel_launch(void* const* d_in, const int* in_sizes, int n_in,
                              void* d_out, int out_size, void* d_ws, size_t ws_size,
                              hipStream_t stream){
  // ---- regression guards ----
  static const int EXP_SIZES[21] = {
    2048*512, 2048*2048, 2048*2048,
    512*256, 256, 256*62, 62, 62*64, 64,
    256*256, 256, 62*62, 62, 64*64, 64,
    64*64, 64, 64*64, 64, 64*64, 64
  };
  float sentinel = 0.f;
  if (n_in != 21) sentinel = 8800000.f;
  if (sentinel == 0.f){
    for (int i = 0; i < 21; ++i)
      if (in_sizes[i] != EXP_SIZES[i]){ sentinel = 100000.f*(float)(i+1); break; }
  }
  if (sentinel == 0.f && out_size != 2048*64) sentinel = 6600000.f;

  // ---- workspace layout ----
  size_t off = 0;
  int*   dflag  = (int*)  wso(d_ws, off, 256);
  int*   ap_cnt = (int*)  wso(d_ws, off, NN*4);
  int*   ap_idx = (int*)  wso(d_ws, off, NN*64*4);
  u64*   colA   = (u64*)  wso(d_ws, off, (size_t)NN*32*8);
  u64*   colB   = (u64*)  wso(d_ws, off, (size_t)NN*32*8);
  u64*   colU   = (u64*)  wso(d_ws, off, (size_t)NN*32*8);
  u64*   rowb   = (u64*)  wso(d_ws, off, (size_t)NN*32*8);
  float* dinv   = (float*)wso(d_ws, off, NN*4);
  float* xf     = (float*)wso(d_ws, off, (size_t)NN*512*4);
  float* part   = (float*)wso(d_ws, off, (size_t)16*NN*64*4);   // 8 MB split-K partials
  float *tl1 = (float*)wso(d_ws, off, 256*512*4), *tg1 = (float*)wso(d_ws, off, 256*256*4);
  float *tl2 = (float*)wso(d_ws, off,  64*256*4), *tg2 = (float*)wso(d_ws, off,  64*64*4);
  float *tl3 = (float*)wso(d_ws, off,   64*64*4), *tg3 = (float*)wso(d_ws, off,  64*64*4);
  float *tg4 = (float*)wso(d_ws, off,   64*64*4), *tg5 = (float*)wso(d_ws, off,  64*64*4);
  float *tg6 = (float*)wso(d_ws, off,   64*64*4);
  float *obl1 = (float*)wso(d_ws, off, 256*4), *obg1 = (float*)wso(d_ws, off, 256*4);
  float *obl2 = (float*)wso(d_ws, off, 64*4),  *obg2 = (float*)wso(d_ws, off, 64*4);
  float *obl3 = (float*)wso(d_ws, off, 64*4),  *obg3 = (float*)wso(d_ws, off, 64*4);
  float *obg4 = (float*)wso(d_ws, off, 64*4),  *obg5 = (float*)wso(d_ws, off, 64*4);
  float *obg6 = (float*)wso(d_ws, off, 64*4);
  float* hF   = (float*)wso(d_ws, off, (size_t)NN*256*4);
  float* zs   = (float*)wso(d_ws, off, (size_t)NN*256*4);
  float* xF   = (float*)wso(d_ws, off, (size_t)NN*256*4);

  if (sentinel == 0.f && off > ws_size) sentinel = 7700000.f;

  if (sentinel != 0.f){
    sentinel_kernel<<<(NN*64 + 255)/256, 256, 0, stream>>>((float*)d_out, sentinel);
    return;
  }

  const void* x_in = d_in[0];
  const void* An   = d_in[1];
  const void* Ap   = d_in[2];

  hipMemsetAsync(dflag, 0, 4, stream);
  probe_kernel<<<256, 256, 0, stream>>>((const u32*)Ap, dflag);
  hipMemsetAsync(ap_cnt, 0, NN*sizeof(int), stream);
  csc_kernel<<<(NN*NN)/256, 256, 0, stream>>>(Ap, ap_cnt, ap_idx, dflag);
  negbits_kernel<<<(NN*32)/256, 256, 0, stream>>>(An, colA, colU, dflag);
  convx_kernel<<<(NN*512)/256, 256, 0, stream>>>(x_in, xf, dflag);

  PrepArgs pa;
  pa.wl1=d_in[3];  pa.bl1=d_in[4];
  pa.wl2=d_in[5];  pa.bl2=d_in[6];
  pa.wl3=d_in[7];  pa.bl3=d_in[8];
  pa.wg1=d_in[9];  pa.bg1=d_in[10];
  pa.wg2=d_in[11]; pa.bg2=d_in[12];
  pa.wg3=d_in[13]; pa.bg3=d_in[14];
  pa.wg4=d_in[15]; pa.bg4=d_in[16];
  pa.wg5=d_in[17]; pa.bg5=d_in[18];
  pa.wg6=d_in[19]; pa.bg6=d_in[20];
  pa.tl1=tl1; pa.tg1=tg1; pa.tl2=tl2; pa.tg2=tg2; pa.tl3=tl3;
  pa.tg3=tg3; pa.tg4=tg4; pa.tg5=tg5; pa.tg6=tg6;
  pa.obl1=obl1; pa.obg1=obg1; pa.obl2=obl2; pa.obg2=obg2; pa.obl3=obl3;
  pa.obg3=obg3; pa.obg4=obg4; pa.obg5=obg5; pa.obg6=obg6;
  pa.flag = dflag;
  prep_kernel<<<512, 256, 0, stream>>>(pa);

  u64 *src = colA, *dst = colB;
  const float wgts[6]  = {1.f, 1.f, 0.5f, 0.5f, 0.25f, 0.25f};
  const int   relus[6] = {1, 1, 1, 1, 1, 0};

  for (int s = 0; s < 6; ++s){
    if (s > 0){
      expand_kernel<<<(NN*32)/256, 256, 0, stream>>>(src, dst, colU, ap_cnt, ap_idx);
      u64* t = src; src = dst; dst = t;
    }
    bittrans_kernel<<<dim3(32,32), 64, 0, stream>>>(colU, rowb);
    degb_kernel<<<NN/256, 256, 0, stream>>>(rowb, dinv);

    if (s == 0){
      mgemm_kernel<0><<<dim3(32,4), 256, 0, stream>>>(xf, tl1, 256, 512, obl1, nullptr, hF);
      mgemm_kernel<1><<<dim3(32,4), 256, 0, stream>>>(hF, tg1, 256, 256, nullptr, dinv, zs);
      maggp_kernel<256><<<dim3(32,4,4), 256, 0, stream>>>(zs, rowb, part, 512);
      magge_kernel<256><<<(NN*256)/256, 256, 0, stream>>>(part, zs, hF, obg1, dinv, 4,
                                                          wgts[0], relus[0], xF, nullptr);
    } else if (s == 1){
      mgemm_kernel<0><<<dim3(32,1), 256, 0, stream>>>(xF, tl2, 64, 256, obl2, nullptr, hF);
      mgemm_kernel<1><<<dim3(32,1), 256, 0, stream>>>(hF, tg2, 64, 64, nullptr, dinv, zs);
      maggp_kernel<64><<<dim3(32,1,16), 256, 0, stream>>>(zs, rowb, part, 128);
      magge_kernel<64><<<(NN*64)/256, 256, 0, stream>>>(part, zs, hF, obg2, dinv, 16,
                                                        wgts[1], relus[1], xF, nullptr);
    } else if (s == 2){
      mgemm_kernel<0><<<dim3(32,1), 256, 0, stream>>>(xF, tl3, 64, 64, obl3, nullptr, hF);
      mgemm_kernel<1><<<dim3(32,1), 256, 0, stream>>>(hF, tg3, 64, 64, nullptr, dinv, zs);
      maggp_kernel<64><<<dim3(32,1,16), 256, 0, stream>>>(zs, rowb, part, 128);
      magge_kernel<64><<<(NN*64)/256, 256, 0, stream>>>(part, zs, hF, obg3, dinv, 16,
                                                        wgts[2], relus[2], xF, nullptr);
    } else {
      const float* tg = (s == 3) ? tg4 : (s == 4) ? tg5 : tg6;
      const float* ob = (s == 3) ? obg4 : (s == 4) ? obg5 : obg6;
      mgemm_kernel<1><<<dim3(32,1), 256, 0, stream>>>(xF, tg, 64, 64, nullptr, dinv, zs);
      maggp_kernel<64><<<dim3(32,1,16), 256, 0, stream>>>(zs, rowb, part, 128);
      float* outD = (s == 5) ? (float*)d_out : nullptr;
      magge_kernel<64><<<(NN*64)/256, 256, 0, stream>>>(part, zs, xF, ob, dinv, 16,
                                                        wgts[s], relus[s], xF, outD);
    }
  }
}

// Round 12
// 369.198 us; speedup vs baseline: 28.4083x; 1.0660x over previous
//
#include <hip/hip_runtime.h>

typedef unsigned short u16;
typedef unsigned int   u32;
typedef unsigned long long u64;
typedef __attribute__((ext_vector_type(8))) short short8;
typedef __attribute__((ext_vector_type(4))) float f32x4;

#define NN 2048

__device__ __forceinline__ float b2f(u16 u){ union { u32 i; float f; } x; x.i = ((u32)u)<<16; return x.f; }
__device__ __forceinline__ u16 f2b(float f){
  u32 u = __float_as_uint(f);
  u32 r = (u + 0x7fffu + ((u>>16)&1u)) >> 16;
  return (u16)r;
}
__device__ __forceinline__ float ldf(const void* p, size_t i, int bf){
  return bf ? b2f(((const u16*)p)[i]) : ((const float*)p)[i];
}
__device__ __forceinline__ void splitbf(float v, u16& h, u16& l){
  h = f2b(v);
  l = f2b(v - b2f(h));
}

// ---------------- diagnostic sentinel (f32 out) ------------------------------
__global__ __launch_bounds__(256) void sentinel_kernel(float* __restrict__ out, float val){
  int g = blockIdx.x*256 + threadIdx.x;
  if (g < NN*64) out[g] = val;
}

// ---------------- dtype probe (parallel): fp32 words are 0 / 0x3F800000 -----
__global__ __launch_bounds__(256) void probe_kernel(const u32* __restrict__ ap, int* __restrict__ flag){
  int i = blockIdx.x*256 + threadIdx.x;   // 65536 words
  u32 w = ap[i];
  if (w != 0u && w != 0x3F800000u) atomicOr(flag, 1);
}

// ---------------- CSC of A_pos (per-column nnz lists, cap 64) ----------------
__global__ __launch_bounds__(256) void csc_kernel(const void* __restrict__ Ap,
                                                  int* __restrict__ cnt, int* __restrict__ idx,
                                                  const int* __restrict__ flag){
  int bf = *flag;
  size_t e = (size_t)blockIdx.x*256 + threadIdx.x;   // e = k*2048 + j
  int k = (int)(e >> 11), j = (int)(e & 2047);
  if (ldf(Ap, e, bf) > 0.f){
    int p = atomicAdd(&cnt[j], 1);
    if (p < 64) idx[j*64 + p] = k;
  }
}

// --------------- column bitsets of A_neg: last/union init --------------------
__global__ __launch_bounds__(256) void negbits_kernel(const void* __restrict__ An,
                                                      u64* __restrict__ last, u64* __restrict__ uni,
                                                      const int* __restrict__ flag){
  int bf = *flag;
  int g = blockIdx.x*256 + threadIdx.x;   // 65536 = 2048 cols * 32 words
  int j = g & 2047, w = g >> 11;
  u64 bits = 0;
  for (int b = 0; b < 64; ++b){
    float v = ldf(An, (size_t)(w*64 + b)*NN + j, bf);
    bits |= (u64)(v > 0.f) << b;
  }
  last[(size_t)j*32 + w] = bits;
  uni [(size_t)j*32 + w] = bits;
}

// --------------- expansion + deg-zero for this stage ------------------------
__global__ __launch_bounds__(256) void expand_kernel(const u64* __restrict__ src, u64* __restrict__ dst,
                                                     u64* __restrict__ uni,
                                                     const int* __restrict__ cnt, const int* __restrict__ idx,
                                                     int* __restrict__ deg){
  int g = blockIdx.x*256 + threadIdx.x;   // 65536
  if (g < NN) deg[g] = 0;                 // zero before this stage's bittrans accumulates
  int w = g & 31, j = g >> 5;
  int c = cnt[j]; c = (c > 64) ? 64 : c;
  const int* lst = idx + j*64;
  u64 acc = 0;
  for (int t = 0; t < c; ++t) acc |= src[(size_t)lst[t]*32 + w];
  dst[(size_t)j*32 + w] = acc;
  uni[(size_t)j*32 + w] |= acc;
}

// --------------- 64x64 bit transpose + row-degree accumulation --------------
__global__ __launch_bounds__(64) void bittrans_kernel(const u64* __restrict__ colb, u64* __restrict__ rowb,
                                                      int* __restrict__ deg){
  __shared__ u64 lds[64];
  int wi = blockIdx.x, wj = blockIdx.y;
  int t = threadIdx.x;
  lds[t] = colb[(size_t)(wj*64 + t)*32 + wi];
  __syncthreads();
  u64 out = 0;
#pragma unroll
  for (int tt = 0; tt < 64; ++tt) out |= ((lds[tt] >> t) & 1ULL) << tt;
  rowb[(size_t)(wi*64 + t)*32 + wj] = out;
  atomicAdd(&deg[wi*64 + t], (int)__popcll(out));
}

// --------------- split-bf16 MFMA GEMM: C[i][n] = sum_k A[i][k]*Bt[n][k] -----
// MODE 0: + bias[n] ; MODE 1: * 1/sqrt(deg[i]+1)
template<int MODE>
__global__ __launch_bounds__(256) void mgemm_kernel(const float* __restrict__ A, const float* __restrict__ Bt,
                                                    int N, int K,
                                                    const float* __restrict__ bias, const int* __restrict__ deg,
                                                    float* __restrict__ outF){
  constexpr int LDT = 72;
  __shared__ u16 Ah[64*LDT], Al[64*LDT], Bh[64*LDT], Bl[64*LDT];
  const int m0 = blockIdx.x*64, n0 = blockIdx.y*64;
  const int tid = threadIdx.x;
  const int wave = tid >> 6, lane = tid & 63;
  const int wm = (wave>>1)*32, wn = (wave&1)*32;
  const int q = lane >> 4, l16 = lane & 15;
  f32x4 acc00 = {}, acc01 = {}, acc10 = {}, acc11 = {};
  const int sr = tid >> 2, sc = (tid & 3)*16;
  for (int k0 = 0; k0 < K; k0 += 64){
    const float* Ag = A  + (size_t)(m0+sr)*K + k0 + sc;
    const float* Bg = Bt + (size_t)(n0+sr)*K + k0 + sc;
#pragma unroll
    for (int v4 = 0; v4 < 4; ++v4){
      float4 av = ((const float4*)Ag)[v4];
      float4 bv = ((const float4*)Bg)[v4];
      int o = sr*LDT + sc + v4*4;
      splitbf(av.x, Ah[o+0], Al[o+0]); splitbf(av.y, Ah[o+1], Al[o+1]);
      splitbf(av.z, Ah[o+2], Al[o+2]); splitbf(av.w, Ah[o+3], Al[o+3]);
      splitbf(bv.x, Bh[o+0], Bl[o+0]); splitbf(bv.y, Bh[o+1], Bl[o+1]);
      splitbf(bv.z, Bh[o+2], Bl[o+2]); splitbf(bv.w, Bh[o+3], Bl[o+3]);
    }
    __syncthreads();
#pragma unroll
    for (int ks = 0; ks < 2; ++ks){
      const int kb = ks*32 + q*8;
      short8 ah0 = *(const short8*)&Ah[(wm      + l16)*LDT + kb];
      short8 al0 = *(const short8*)&Al[(wm      + l16)*LDT + kb];
      short8 ah1 = *(const short8*)&Ah[(wm + 16 + l16)*LDT + kb];
      short8 al1 = *(const short8*)&Al[(wm + 16 + l16)*LDT + kb];
      short8 bh0 = *(const short8*)&Bh[(wn      + l16)*LDT + kb];
      short8 bl0 = *(const short8*)&Bl[(wn      + l16)*LDT + kb];
      short8 bh1 = *(const short8*)&Bh[(wn + 16 + l16)*LDT + kb];
      short8 bl1 = *(const short8*)&Bl[(wn + 16 + l16)*LDT + kb];
      acc00 = __builtin_amdgcn_mfma_f32_16x16x32_bf16(ah0, bh0, acc00, 0, 0, 0);
      acc00 = __builtin_amdgcn_mfma_f32_16x16x32_bf16(ah0, bl0, acc00, 0, 0, 0);
      acc00 = __builtin_amdgcn_mfma_f32_16x16x32_bf16(al0, bh0, acc00, 0, 0, 0);
      acc01 = __builtin_amdgcn_mfma_f32_16x16x32_bf16(ah0, bh1, acc01, 0, 0, 0);
      acc01 = __builtin_amdgcn_mfma_f32_16x16x32_bf16(ah0, bl1, acc01, 0, 0, 0);
      acc01 = __builtin_amdgcn_mfma_f32_16x16x32_bf16(al0, bh1, acc01, 0, 0, 0);
      acc10 = __builtin_amdgcn_mfma_f32_16x16x32_bf16(ah1, bh0, acc10, 0, 0, 0);
      acc10 = __builtin_amdgcn_mfma_f32_16x16x32_bf16(ah1, bl0, acc10, 0, 0, 0);
      acc10 = __builtin_amdgcn_mfma_f32_16x16x32_bf16(al1, bh0, acc10, 0, 0, 0);
      acc11 = __builtin_amdgcn_mfma_f32_16x16x32_bf16(ah1, bh1, acc11, 0, 0, 0);
      acc11 = __builtin_amdgcn_mfma_f32_16x16x32_bf16(ah1, bl1, acc11, 0, 0, 0);
      acc11 = __builtin_amdgcn_mfma_f32_16x16x32_bf16(al1, bh1, acc11, 0, 0, 0);
    }
    __syncthreads();
  }
#pragma unroll
  for (int mi = 0; mi < 2; ++mi)
#pragma unroll
  for (int ni = 0; ni < 2; ++ni){
    f32x4 a = (mi == 0) ? ((ni == 0) ? acc00 : acc01) : ((ni == 0) ? acc10 : acc11);
#pragma unroll
    for (int r = 0; r < 4; ++r){
      int i = m0 + wm + mi*16 + q*4 + r;
      int n = n0 + wn + ni*16 + l16;
      float v = a[r];
      if constexpr (MODE == 0) v += bias[n];
      else                     v *= 1.0f / sqrtf((float)(deg[i] + 1));
      outF[(size_t)i*N + n] = v;
    }
  }
}

// --------------- split-K bitmask-MFMA aggregation (partials) ----------------
template<int F>
__global__ __launch_bounds__(256) void maggp_kernel(const float* __restrict__ zs,
                                                    const u64* __restrict__ rowb,
                                                    float* __restrict__ part, int KCH){
  const int m0 = blockIdx.x*64, n0 = blockIdx.y*64, kc0 = blockIdx.z*KCH;
  const int tid = threadIdx.x;
  const int wave = tid >> 6, lane = tid & 63;
  const int wm = (wave>>1)*32, wn = (wave&1)*32;
  const int q = lane >> 4, l16 = lane & 15;
  f32x4 acc00 = {}, acc01 = {}, acc10 = {}, acc11 = {};
  for (int k0 = kc0; k0 < kc0 + KCH; k0 += 64){
    const int wd = k0 >> 6;
    u64 w0 = rowb[(size_t)(m0 + wm      + l16)*32 + wd];
    u64 w1 = rowb[(size_t)(m0 + wm + 16 + l16)*32 + wd];
#pragma unroll
    for (int ks = 0; ks < 2; ++ks){
      const int kk = ks*32 + q*8;
      u32 by0 = (u32)(w0 >> kk) & 0xFFu;
      u32 by1 = (u32)(w1 >> kk) & 0xFFu;
      short8 a0, a1;
#pragma unroll
      for (int j = 0; j < 8; ++j){
        a0[j] = (short)(((by0 >> j) & 1u) ? 0x3F80 : 0);
        a1[j] = (short)(((by1 >> j) & 1u) ? 0x3F80 : 0);
      }
      const float* B0 = zs + (size_t)(k0 + kk)*F + n0;
      short8 bh0, bl0, bh1, bl1;
#pragma unroll
      for (int j = 0; j < 8; ++j){
        u16 hh, ll;
        splitbf(B0[(size_t)j*F + wn      + l16], hh, ll); bh0[j] = (short)hh; bl0[j] = (short)ll;
        splitbf(B0[(size_t)j*F + wn + 16 + l16], hh, ll); bh1[j] = (short)hh; bl1[j] = (short)ll;
      }
      acc00 = __builtin_amdgcn_mfma_f32_16x16x32_bf16(a0, bh0, acc00, 0, 0, 0);
      acc00 = __builtin_amdgcn_mfma_f32_16x16x32_bf16(a0, bl0, acc00, 0, 0, 0);
      acc01 = __builtin_amdgcn_mfma_f32_16x16x32_bf16(a0, bh1, acc01, 0, 0, 0);
      acc01 = __builtin_amdgcn_mfma_f32_16x16x32_bf16(a0, bl1, acc01, 0, 0, 0);
      acc10 = __builtin_amdgcn_mfma_f32_16x16x32_bf16(a1, bh0, acc10, 0, 0, 0);
      acc10 = __builtin_amdgcn_mfma_f32_16x16x32_bf16(a1, bl0, acc10, 0, 0, 0);
      acc11 = __builtin_amdgcn_mfma_f32_16x16x32_bf16(a1, bh1, acc11, 0, 0, 0);
      acc11 = __builtin_amdgcn_mfma_f32_16x16x32_bf16(a1, bl1, acc11, 0, 0, 0);
    }
  }
  float* p = part + (size_t)blockIdx.z*NN*F;
#pragma unroll
  for (int mi = 0; mi < 2; ++mi)
#pragma unroll
  for (int ni = 0; ni < 2; ++ni){
    f32x4 a = (mi == 0) ? ((ni == 0) ? acc00 : acc01) : ((ni == 0) ? acc10 : acc11);
#pragma unroll
    for (int r = 0; r < 4; ++r){
      int i = m0 + wm + mi*16 + q*4 + r;
      int n = n0 + wn + ni*16 + l16;
      p[(size_t)i*F + n] = a[r];
    }
  }
}

// --------------- split-K reduce + GCN epilogue ------------------------------
template<int F>
__global__ __launch_bounds__(256) void magge_kernel(const float* __restrict__ part,
                                                    const float* __restrict__ zs, const float* __restrict__ h,
                                                    const float* __restrict__ bias, const int* __restrict__ deg,
                                                    int KS, float wgt, int doRelu,
                                                    float* __restrict__ outF, float* __restrict__ outD){
  int g = blockIdx.x*256 + threadIdx.x;   // 2048*F
  int n = g & (F - 1);
  int i = g / F;
  float y = 0.f;
  for (int s = 0; s < KS; ++s) y += part[(size_t)s*NN*F + g];
  float di = 1.0f / sqrtf((float)(deg[i] + 1));
  float o = di*(y + zs[g]) + bias[n];
  if (doRelu) o = fmaxf(o, 0.f);
  float xn = h[g] + wgt*o;
  outF[g] = xn;
  if (outD) outD[g] = xn;
}

// --------------- weight transpose + padding + x conversion, all f32 ---------
struct PrepArgs {
  const void *x; float* xf;
  const void *wl1,*bl1,*wl2,*bl2,*wl3,*bl3,*wg1,*bg1,*wg2,*bg2,*wg3,*bg3,*wg4,*bg4,*wg5,*bg5,*wg6,*bg6;
  float *tl1,*tg1,*tl2,*tg2,*tl3,*tg3,*tg4,*tg5,*tg6;
  float *obl1,*obg1,*obl2,*obg2,*obl3,*obg3,*obg4,*obg5,*obg6;
  const int* flag;
};

__global__ __launch_bounds__(256) void prep_kernel(PrepArgs a){
  int bf = *a.flag;
  int t = blockIdx.x*256 + threadIdx.x;     // 131072 threads
  for (size_t i = t; i < (size_t)NN*512; i += 131072) a.xf[i] = ldf(a.x, i, bf);
  if (t < 256*512){ int n = t>>9, k = t&511; a.tl1[t] = ldf(a.wl1, (size_t)k*256 + n, bf); }
  if (t < 256*256){ int n = t>>8, k = t&255; a.tg1[t] = ldf(a.wg1, (size_t)k*256 + n, bf); }
  if (t <  64*256){ int n = t>>8, k = t&255; a.tl2[t] = (n < 62) ? ldf(a.wl2, (size_t)k*62 + n, bf) : 0.f; }
  if (t <  64*64){
    int n = t>>6, k = t&63;
    a.tg2[t] = (n < 62 && k < 62) ? ldf(a.wg2, (size_t)k*62 + n, bf) : 0.f;
    a.tl3[t] = (k < 62) ? ldf(a.wl3, (size_t)k*64 + n, bf) : 0.f;
    a.tg3[t] = ldf(a.wg3, (size_t)k*64 + n, bf);
    a.tg4[t] = ldf(a.wg4, (size_t)k*64 + n, bf);
    a.tg5[t] = ldf(a.wg5, (size_t)k*64 + n, bf);
    a.tg6[t] = ldf(a.wg6, (size_t)k*64 + n, bf);
  }
  if (t < 256){ a.obl1[t] = ldf(a.bl1, t, bf); a.obg1[t] = ldf(a.bg1, t, bf); }
  if (t < 64){
    a.obl2[t] = (t < 62) ? ldf(a.bl2, t, bf) : 0.f;
    a.obg2[t] = (t < 62) ? ldf(a.bg2, t, bf) : 0.f;
    a.obl3[t] = ldf(a.bl3, t, bf);
    a.obg3[t] = ldf(a.bg3, t, bf);
    a.obg4[t] = ldf(a.bg4, t, bf);
    a.obg5[t] = ldf(a.bg5, t, bf);
    a.obg6[t] = ldf(a.bg6, t, bf);
  }
}

static inline char* wso(void* ws, size_t& off, size_t bytes){
  char* p = (char*)ws + off;
  off += (bytes + 255) & ~(size_t)255;
  return p;
}

extern "C" void kernel_launch(void* const* d_in, const int* in_sizes, int n_in,
                              void* d_out, int out_size, void* d_ws, size_t ws_size,
                              hipStream_t stream){
  // ---- regression guards ----
  static const int EXP_SIZES[21] = {
    2048*512, 2048*2048, 2048*2048,
    512*256, 256, 256*62, 62, 62*64, 64,
    256*256, 256, 62*62, 62, 64*64, 64,
    64*64, 64, 64*64, 64, 64*64, 64
  };
  float sentinel = 0.f;
  if (n_in != 21) sentinel = 8800000.f;
  if (sentinel == 0.f){
    for (int i = 0; i < 21; ++i)
      if (in_sizes[i] != EXP_SIZES[i]){ sentinel = 100000.f*(float)(i+1); break; }
  }
  if (sentinel == 0.f && out_size != 2048*64) sentinel = 6600000.f;

  // ---- workspace layout (dflag|ap_cnt|deg contiguous for one memset) ----
  size_t off = 0;
  int*   dflag  = (int*)  wso(d_ws, off, 256);
  int*   ap_cnt = (int*)  wso(d_ws, off, NN*4);
  int*   deg    = (int*)  wso(d_ws, off, NN*4);
  size_t zero_bytes = off;                      // 16640
  int*   ap_idx = (int*)  wso(d_ws, off, NN*64*4);
  u64*   colA   = (u64*)  wso(d_ws, off, (size_t)NN*32*8);
  u64*   colB   = (u64*)  wso(d_ws, off, (size_t)NN*32*8);
  u64*   colU   = (u64*)  wso(d_ws, off, (size_t)NN*32*8);
  u64*   rowb   = (u64*)  wso(d_ws, off, (size_t)NN*32*8);
  float* xf     = (float*)wso(d_ws, off, (size_t)NN*512*4);
  float* part   = (float*)wso(d_ws, off, (size_t)16*NN*64*4);   // 8 MB split-K partials
  float *tl1 = (float*)wso(d_ws, off, 256*512*4), *tg1 = (float*)wso(d_ws, off, 256*256*4);
  float *tl2 = (float*)wso(d_ws, off,  64*256*4), *tg2 = (float*)wso(d_ws, off,  64*64*4);
  float *tl3 = (float*)wso(d_ws, off,   64*64*4), *tg3 = (float*)wso(d_ws, off,  64*64*4);
  float *tg4 = (float*)wso(d_ws, off,   64*64*4), *tg5 = (float*)wso(d_ws, off,  64*64*4);
  float *tg6 = (float*)wso(d_ws, off,   64*64*4);
  float *obl1 = (float*)wso(d_ws, off, 256*4), *obg1 = (float*)wso(d_ws, off, 256*4);
  float *obl2 = (float*)wso(d_ws, off, 64*4),  *obg2 = (float*)wso(d_ws, off, 64*4);
  float *obl3 = (float*)wso(d_ws, off, 64*4),  *obg3 = (float*)wso(d_ws, off, 64*4);
  float *obg4 = (float*)wso(d_ws, off, 64*4),  *obg5 = (float*)wso(d_ws, off, 64*4);
  float *obg6 = (float*)wso(d_ws, off, 64*4);
  float* hF   = (float*)wso(d_ws, off, (size_t)NN*256*4);
  float* zs   = (float*)wso(d_ws, off, (size_t)NN*256*4);
  float* xF   = (float*)wso(d_ws, off, (size_t)NN*256*4);

  if (sentinel == 0.f && off > ws_size) sentinel = 7700000.f;

  if (sentinel != 0.f){
    sentinel_kernel<<<(NN*64 + 255)/256, 256, 0, stream>>>((float*)d_out, sentinel);
    return;
  }

  const void* x_in = d_in[0];
  const void* An   = d_in[1];
  const void* Ap   = d_in[2];

  hipMemsetAsync(d_ws, 0, zero_bytes, stream);   // dflag + ap_cnt + deg (stage 0)
  probe_kernel<<<256, 256, 0, stream>>>((const u32*)Ap, dflag);
  csc_kernel<<<(NN*NN)/256, 256, 0, stream>>>(Ap, ap_cnt, ap_idx, dflag);
  negbits_kernel<<<(NN*32)/256, 256, 0, stream>>>(An, colA, colU, dflag);

  PrepArgs pa;
  pa.x = x_in; pa.xf = xf;
  pa.wl1=d_in[3];  pa.bl1=d_in[4];
  pa.wl2=d_in[5];  pa.bl2=d_in[6];
  pa.wl3=d_in[7];  pa.bl3=d_in[8];
  pa.wg1=d_in[9];  pa.bg1=d_in[10];
  pa.wg2=d_in[11]; pa.bg2=d_in[12];
  pa.wg3=d_in[13]; pa.bg3=d_in[14];
  pa.wg4=d_in[15]; pa.bg4=d_in[16];
  pa.wg5=d_in[17]; pa.bg5=d_in[18];
  pa.wg6=d_in[19]; pa.bg6=d_in[20];
  pa.tl1=tl1; pa.tg1=tg1; pa.tl2=tl2; pa.tg2=tg2; pa.tl3=tl3;
  pa.tg3=tg3; pa.tg4=tg4; pa.tg5=tg5; pa.tg6=tg6;
  pa.obl1=obl1; pa.obg1=obg1; pa.obl2=obl2; pa.obg2=obg2; pa.obl3=obl3;
  pa.obg3=obg3; pa.obg4=obg4; pa.obg5=obg5; pa.obg6=obg6;
  pa.flag = dflag;
  prep_kernel<<<512, 256, 0, stream>>>(pa);

  u64 *src = colA, *dst = colB;
  const float wgts[6]  = {1.f, 1.f, 0.5f, 0.5f, 0.25f, 0.25f};
  const int   relus[6] = {1, 1, 1, 1, 1, 0};

  for (int s = 0; s < 6; ++s){
    if (s > 0){
      expand_kernel<<<(NN*32)/256, 256, 0, stream>>>(src, dst, colU, ap_cnt, ap_idx, deg);
      u64* t = src; src = dst; dst = t;
    }
    bittrans_kernel<<<dim3(32,32), 64, 0, stream>>>(colU, rowb, deg);

    if (s == 0){
      mgemm_kernel<0><<<dim3(32,4), 256, 0, stream>>>(xf, tl1, 256, 512, obl1, nullptr, hF);
      mgemm_kernel<1><<<dim3(32,4), 256, 0, stream>>>(hF, tg1, 256, 256, nullptr, deg, zs);
      maggp_kernel<256><<<dim3(32,4,4), 256, 0, stream>>>(zs, rowb, part, 512);
      magge_kernel<256><<<(NN*256)/256, 256, 0, stream>>>(part, zs, hF, obg1, deg, 4,
                                                          wgts[0], relus[0], xF, nullptr);
    } else if (s == 1){
      mgemm_kernel<0><<<dim3(32,1), 256, 0, stream>>>(xF, tl2, 64, 256, obl2, nullptr, hF);
      mgemm_kernel<1><<<dim3(32,1), 256, 0, stream>>>(hF, tg2, 64, 64, nullptr, deg, zs);
      maggp_kernel<64><<<dim3(32,1,8), 256, 0, stream>>>(zs, rowb, part, 256);
      magge_kernel<64><<<(NN*64)/256, 256, 0, stream>>>(part, zs, hF, obg2, deg, 8,
                                                        wgts[1], relus[1], xF, nullptr);
    } else if (s == 2){
      mgemm_kernel<0><<<dim3(32,1), 256, 0, stream>>>(xF, tl3, 64, 64, obl3, nullptr, hF);
      mgemm_kernel<1><<<dim3(32,1), 256, 0, stream>>>(hF, tg3, 64, 64, nullptr, deg, zs);
      maggp_kernel<64><<<dim3(32,1,8), 256, 0, stream>>>(zs, rowb, part, 256);
      magge_kernel<64><<<(NN*64)/256, 256, 0, stream>>>(part, zs, hF, obg3, deg, 8,
                                                        wgts[2], relus[2], xF, nullptr);
    } else {
      const float* tg = (s == 3) ? tg4 : (s == 4) ? tg5 : tg6;
      const float* ob = (s == 3) ? obg4 : (s == 4) ? obg5 : obg6;
      mgemm_kernel<1><<<dim3(32,1), 256, 0, stream>>>(xF, tg, 64, 64, nullptr, deg, zs);
      maggp_kernel<64><<<dim3(32,1,8), 256, 0, stream>>>(zs, rowb, part, 256);
      float* outD = (s == 5) ? (float*)d_out : nullptr;
      magge_kernel<64><<<(NN*64)/256, 256, 0, stream>>>(part, zs, xF, ob, deg, 8,
                                                        wgts[s], relus[s], xF, outD);
    }
  }
}